// Round 3
// baseline (326.095 us; speedup 1.0000x reference)
//
#include <hip/hip_runtime.h>
#include <hip/hip_bf16.h>
#include <math.h>

// EpisodicMemory fused pipeline for MI355X (gfx950).
// B=16384, HID=1024, SLOTS=64, KD=32.
// Dominant cost: ONE [16384,2048]x[2048,2048] bf16 MFMA GEMM (gate/out weights
// row-interleaved in 16-col groups) with fused sigmoid/GELU/blend epilogue.
// Schedule: 256x256 tile, BK=32, 3-buffer LDS pipeline, counted vmcnt(4),
// raw s_barrier (1/K-tile), XOR-swizzled LDS, setprio around MFMA cluster.

typedef float    f32x4 __attribute__((ext_vector_type(4)));
typedef short    s16x8 __attribute__((ext_vector_type(8)));
typedef unsigned short u16;
typedef unsigned short u16x8 __attribute__((ext_vector_type(8)));

#define MFMA_BF16(a,b,c) __builtin_amdgcn_mfma_f32_16x16x32_bf16((a),(b),(c),0,0,0)

__device__ __forceinline__ void async16(void* lds, const void* g) {
  __builtin_amdgcn_global_load_lds((const __attribute__((address_space(1))) void*)g,
                                   (__attribute__((address_space(3))) void*)lds, 16, 0, 0);
}

__device__ __forceinline__ u16 f2bf(float f) {
  unsigned u = __float_as_uint(f);
  u += 0x7fffu + ((u >> 16) & 1u);   // RNE
  return (u16)(u >> 16);
}
__device__ __forceinline__ float bf2f(u16 h) {
  return __uint_as_float(((unsigned)h) << 16);
}

// ---------------- K0: per-slot prep (keys_with_pos normalized, bias) --------
__global__ void k_prep(const float* __restrict__ mem_keys, const float* __restrict__ pos_table,
                       const int* __restrict__ slot_order, const float* __restrict__ mem_age,
                       const float* __restrict__ mem_conf,
                       float* __restrict__ kwp /*[64][33] padded*/, float* __restrict__ biasv) {
  int s = threadIdx.x;            // 64 threads = 1 wave
  float age  = mem_age[s];
  float freq = fmaxf(age, 1.0f);
  float fm = freq;
  #pragma unroll
  for (int o = 32; o; o >>= 1) fm = fmaxf(fm, __shfl_xor(fm, o));
  float freq_norm = logf(freq + 1.0f) / (logf(fm + 2.0f) + 1e-8f);
  float recency = expf(-age * (1.0f/200.0f));
  biasv[s] = 0.2f*recency + 0.15f*freq_norm + 0.1f*mem_conf[s] + 0.08f;

  int idx = slot_order[s] & 63;   // % SLOTS (values are arange, nonneg)
  float k[32]; float ss = 0.f;
  #pragma unroll
  for (int d = 0; d < 32; d++) {
    float v = mem_keys[s*32+d] + 0.1f*pos_table[idx*32+d];
    k[d] = v; ss += v*v;
  }
  float inv = 1.0f / fmaxf(sqrtf(ss), 1e-12f);
  #pragma unroll
  for (int d = 0; d < 32; d++) kwp[s*33+d] = k[d]*inv;
}

// ---------------- K1: fp32 -> bf16 conversions ------------------------------
// Weights go to Wcat [2048][2048]: row p = g*32 + h*16 + c holds
// (h==0 ? gate_w : out_w) row (g*16+c). So a 32-row group of Wcat = 16 gate
// cols then the SAME 16 out cols -> fused epilogue pairs stay intra-lane.
__global__ __launch_bounds__(256) void k_convert(
    const float* __restrict__ x, const float* __restrict__ gate_w,
    const float* __restrict__ out_w, const float* __restrict__ key_w,
    const float* __restrict__ mem_vals,
    u16* __restrict__ A, u16* __restrict__ Wcat,
    u16* __restrict__ Wk, u16* __restrict__ Vals) {
  const int NX = 4194304, NW = 524288, NK = 8192, NV = 16384;  // float4 groups
  const int total = NX + 2*NW + NK + NV;
  for (int g = blockIdx.x*256 + threadIdx.x; g < total; g += gridDim.x*256) {
    float4 v; u16* dst;
    if (g < NX) {                       // x -> combined[:, 0:1024]
      v = ((const float4*)x)[g];
      int r = g >> 8, c4 = g & 255;
      dst = A + ((size_t)r*2048 + c4*4);
    } else if (g < NX+NW) {             // gate_w -> Wcat interleaved
      int t = g-NX; v = ((const float4*)gate_w)[t];
      int row = t >> 9, grp = t & 511;
      int p = ((row>>4)<<5) + (row&15);
      dst = Wcat + ((size_t)p*2048 + grp*4);
    } else if (g < NX+2*NW) {           // out_w -> Wcat interleaved (+16)
      int t = g-NX-NW; v = ((const float4*)out_w)[t];
      int row = t >> 9, grp = t & 511;
      int p = ((row>>4)<<5) + 16 + (row&15);
      dst = Wcat + ((size_t)p*2048 + grp*4);
    } else if (g < NX+2*NW+NK) {
      int t = g-NX-2*NW; v = ((const float4*)key_w)[t];   dst = Wk + (size_t)t*4;
    } else {
      int t = g-NX-2*NW-NK; v = ((const float4*)mem_vals)[t]; dst = Vals + (size_t)t*4;
    }
    ushort4 o; o.x=f2bf(v.x); o.y=f2bf(v.y); o.z=f2bf(v.z); o.w=f2bf(v.w);
    *(ushort4*)dst = o;
  }
}

// ---------------- K2a: qk = x @ key_w^T  (thin MFMA GEMM) -------------------
__global__ __launch_bounds__(256) void k_qk(const u16* __restrict__ A, const u16* __restrict__ Wk,
                                            float* __restrict__ qk) {
  __shared__ __align__(16) u16 sA[64*64];
  __shared__ __align__(16) u16 sB[32*64];
  int tid = threadIdx.x, lane = tid & 63, w = tid >> 6;
  int r0 = blockIdx.x * 64;
  f32x4 acc[2] = { {0.f,0.f,0.f,0.f}, {0.f,0.f,0.f,0.f} };
  for (int k0 = 0; k0 < 1024; k0 += 64) {
    const char* Ab = (const char*)A + ((size_t)r0*2048 + k0)*2;   // A row stride 4096 B
    #pragma unroll
    for (int i = 0; i < 2; i++) {
      int cidx = tid + i*256;                  // 512 chunks of 16 B
      async16((char*)sA + cidx*16, Ab + (size_t)(cidx>>3)*4096 + (size_t)(cidx&7)*16);
    }
    { const char* Bb = (const char*)Wk + (size_t)k0*2;            // Wk row stride 2048 B
      async16((char*)sB + tid*16, Bb + (size_t)(tid>>3)*2048 + (size_t)(tid&7)*16); }
    __syncthreads();
    #pragma unroll
    for (int kk = 0; kk < 2; kk++) {
      int kb = kk*32 + (lane>>4)*8;
      s16x8 a  = *(const s16x8*)&sA[(w*16 + (lane&15))*64 + kb];
      s16x8 b0 = *(const s16x8*)&sB[(lane&15)*64 + kb];
      s16x8 b1 = *(const s16x8*)&sB[((lane&15)+16)*64 + kb];
      acc[0] = MFMA_BF16(a, b0, acc[0]);
      acc[1] = MFMA_BF16(a, b1, acc[1]);
    }
    __syncthreads();
  }
  int rr = (lane>>4)*4, cc = lane&15;
  #pragma unroll
  for (int n = 0; n < 2; n++)
    #pragma unroll
    for (int i = 0; i < 4; i++)
      qk[(size_t)(r0 + w*16 + rr + i)*32 + n*16 + cc] = acc[n][i];
}

// ---------------- K2b: softmax over slots + retrieved = attn @ mem_vals -----
__global__ __launch_bounds__(256) void k_retr(const float* __restrict__ qk,
                                              const float* __restrict__ kwp,
                                              const float* __restrict__ biasv,
                                              const u16* __restrict__ Vals,
                                              u16* __restrict__ A) {
  __shared__ float sK[64*33];
  __shared__ float sBias[64];
  __shared__ float sQn[16*32];
  __shared__ float sAttn[16*64];
  int tid = threadIdx.x, lane = tid & 63, w = tid >> 6;
  int row0 = blockIdx.x * 16;
  for (int i = tid; i < 64*33; i += 256) sK[i] = kwp[i];
  if (tid < 64) sBias[tid] = biasv[tid];
  __syncthreads();

  int d = lane & 31;
  for (int j = 0; j < 4; j++) {
    int rl = w*4 + j;
    float v = qk[(size_t)(row0+rl)*32 + d];
    float sq = v*v;
    #pragma unroll
    for (int o = 16; o; o >>= 1) sq += __shfl_xor(sq, o);   // 32-lane group sum
    float qn = v / fmaxf(sqrtf(sq), 1e-12f);
    if (lane < 32) sQn[rl*32 + d] = qn;
    float accs = 0.f;
    #pragma unroll
    for (int dd = 0; dd < 32; dd++) accs += sK[lane*33+dd] * sQn[rl*32+dd];
    float sim = accs * 0.17677669529663687f;   // 1/sqrt(32)
    float sal = fminf(fmaxf(0.45f*sim + sBias[lane], 0.0f), 1.0f);
    float mx = sal;
    #pragma unroll
    for (int o = 32; o; o >>= 1) mx = fmaxf(mx, __shfl_xor(mx, o));
    float e = expf(sal - mx);
    float sm = e;
    #pragma unroll
    for (int o = 32; o; o >>= 1) sm += __shfl_xor(sm, o);
    sAttn[rl*64 + lane] = e / sm;
  }
  __syncthreads();

  float acc[4][16];
  #pragma unroll
  for (int j = 0; j < 4; j++)
    #pragma unroll
    for (int i = 0; i < 16; i++) acc[j][i] = 0.f;
  const u16* vp = Vals + lane*16;
  for (int s = 0; s < 64; s++) {
    s16x8 v0 = *(const s16x8*)(vp + (size_t)s*1024);
    s16x8 v1 = *(const s16x8*)(vp + (size_t)s*1024 + 8);
    float vf[16];
    #pragma unroll
    for (int i = 0; i < 8; i++) { vf[i] = bf2f((u16)v0[i]); vf[8+i] = bf2f((u16)v1[i]); }
    #pragma unroll
    for (int j = 0; j < 4; j++) {
      float a = sAttn[(w*4+j)*64 + s];
      #pragma unroll
      for (int i = 0; i < 16; i++) acc[j][i] += a * vf[i];
    }
  }
  #pragma unroll
  for (int j = 0; j < 4; j++) {
    int r = row0 + w*4 + j;
    u16x8 o0, o1;
    #pragma unroll
    for (int i = 0; i < 8; i++) { o0[i] = f2bf(acc[j][i]); o1[i] = f2bf(acc[j][8+i]); }
    u16* dst = A + (size_t)r*2048 + 1024 + lane*16;   // combined[:, 1024:2048]
    *(u16x8*)dst = o0;
    *(u16x8*)(dst + 8) = o1;
  }
}

// ---------------- K3: single interleaved GEMM + fused epilogue --------------
// C = combined[16384,2048] @ Wcat[2048,2048]^T. Wcat rows alternate gate/out
// in 16-groups, so acc[m][n] (n even)=gate, acc[m][n+1]=out for SAME ocol.
// 256x256 tile, BK=32, 8 waves (2M x 4N), 3-buffer LDS pipeline:
//   compute tile t from buf[t%3], stage tile t+2 into buf[(t+2)%3].
// vmcnt(4) counted wait (tile t+1's 4 loads stay in flight across barrier).
__global__ __launch_bounds__(512, 2) void k_gemm(
    const u16* __restrict__ A, const u16* __restrict__ Wcat,
    const float* __restrict__ x, const float* __restrict__ out_b,
    const float* __restrict__ gate_b, float* __restrict__ y) {
  // 3 buffers: A tile 256x32 bf16 (16 KB), B tile 256x32 bf16 (16 KB) = 96 KB
  __shared__ __align__(16) u16 sA[3][256*32];
  __shared__ __align__(16) u16 sB[3][256*32];

  const int tid = threadIdx.x, lane = tid & 63, w = tid >> 6;
  const int ln15 = lane & 15, hi = lane >> 4;
  const int wm = w >> 2, wn = w & 3;          // 2M x 4N waves; wave out 128x64

  // XCD-chunked swizzle: 512 wgs, 8 XCDs, 64 consecutive per XCD = one
  // colblk column (weight panel 1 MB resident in per-XCD L2), A via L3.
  int wg = (blockIdx.x & 7) * 64 + (blockIdx.x >> 3);
  int colblk = wg >> 6;          // 0..7
  int rowblk = wg & 63;          // 0..63
  const size_t r0 = (size_t)rowblk * 256;
  const size_t c0 = (size_t)colblk * 256;

  const u16* gA = A    + r0 * 2048;
  const u16* gB = Wcat + c0 * 2048;

  // staging: per thread 2 A-chunks + 2 B-chunks of 16 B per K-tile.
  // chunk idx -> (row = idx>>2, colc = idx&3); source col pre-swizzled so a
  // swizzled ds_read returns logical data (rule: linear LDS dest + inv-swz src).
  #define STAGE_TILE(nxt, kt) do {                                            \
    _Pragma("unroll")                                                         \
    for (int j = 0; j < 2; j++) {                                             \
      int idx = j*512 + tid;                                                  \
      int row = idx >> 2, colc = idx & 3;                                     \
      int scol = colc ^ ((row >> 1) & 3);                                     \
      async16(&sA[nxt][idx*8], gA + (size_t)row*2048 + (kt)*32 + scol*8);     \
      async16(&sB[nxt][idx*8], gB + (size_t)row*2048 + (kt)*32 + scol*8);     \
    }                                                                         \
  } while (0)

  f32x4 acc[8][4];
  #pragma unroll
  for (int m = 0; m < 8; m++)
    #pragma unroll
    for (int n = 0; n < 4; n++) acc[m][n] = {0.f, 0.f, 0.f, 0.f};

  // prologue: tiles 0 and 1 into buffers 0 and 1 (8 loads/thread outstanding)
  STAGE_TILE(0, 0);
  STAGE_TILE(1, 1);

  // swizzled ds_read column slot: depends only on lane (rows stride 16)
  const int sw = (ln15 >> 1) & 3;

  int cur = 0;
  #pragma unroll 1
  for (int kt = 0; kt < 64; ++kt) {
    // tile kt ready when this wave's 4 oldest loads land; tile kt+1's 4 stay
    // in flight. All-waves visibility via the barrier after the wait.
    if (kt < 63) asm volatile("s_waitcnt vmcnt(4)" ::: "memory");
    else         asm volatile("s_waitcnt vmcnt(0)" ::: "memory");
    __builtin_amdgcn_s_barrier();
    asm volatile("" ::: "memory");   // fence: no LDS reads hoisted above barrier

    if (kt < 62) {
      int nxt = cur + 2; if (nxt >= 3) nxt -= 3;
      STAGE_TILE(nxt, kt + 2);
    }

    const u16* sa = &sA[cur][0];
    const u16* sb = &sB[cur][0];
    s16x8 af[8], bfr[4];
    #pragma unroll
    for (int m = 0; m < 8; m++) {
      int row = wm*128 + m*16 + ln15;
      af[m] = *(const s16x8*)&sa[row*32 + ((hi ^ sw) ^ ((row>>1)&3) ^ sw)*8 + (hi ^ sw)*0];
    }
    #pragma unroll
    for (int n = 0; n < 4; n++) {
      int row = wn*64 + n*16 + ln15;
      bfr[n] = *(const s16x8*)&sb[row*32 + ((hi ^ ((row>>1)&3)))*8];
    }

    __builtin_amdgcn_s_setprio(1);
    #pragma unroll
    for (int m = 0; m < 8; m++)
      #pragma unroll
      for (int n = 0; n < 4; n++)
        acc[m][n] = MFMA_BF16(af[m], bfr[n], acc[m][n]);
    __builtin_amdgcn_s_setprio(0);

    cur = (cur == 2) ? 0 : cur + 1;
  }
  #undef STAGE_TILE

  // epilogue: n-pairs (gate=acc[.][n], out=acc[.][n+1]) -> y pre-LN
  int rr = hi * 4;
  #pragma unroll
  for (int n = 0; n < 4; n += 2) {
    int ocol = colblk*128 + wn*32 + (n>>1)*16 + ln15;
    float gbv = gate_b[ocol], obv = out_b[ocol];
    #pragma unroll
    for (int m = 0; m < 8; m++) {
      #pragma unroll
      for (int i = 0; i < 4; i++) {
        size_t r = r0 + wm*128 + m*16 + rr + i;
        float gg = acc[m][n][i]   + gbv;
        float go = acc[m][n+1][i] + obv;
        float h  = 0.5f*go*(1.0f + erff(go*0.70710678118654752f));  // exact gelu
        float sg = 1.0f/(1.0f + __expf(-gg));
        float rv = bf2f(A[r*2048 + 1024 + ocol]);
        float xv = x[r*1024 + ocol];
        y[r*1024 + ocol] = h + sg*rv + (1.0f - sg)*xv;
      }
    }
  }
}

// ---------------- K4: LayerNorm in place (wave per row) ---------------------
__global__ __launch_bounds__(256) void k_ln(float* __restrict__ y, const float* __restrict__ g,
                                            const float* __restrict__ b) {
  int row  = blockIdx.x*4 + (threadIdx.x >> 6);
  int lane = threadIdx.x & 63;
  float4* p = (float4*)(y + (size_t)row*1024);
  float4 v[4];
  #pragma unroll
  for (int i = 0; i < 4; i++) v[i] = p[lane + 64*i];
  float s = 0.f;
  #pragma unroll
  for (int i = 0; i < 4; i++) s += v[i].x + v[i].y + v[i].z + v[i].w;
  #pragma unroll
  for (int o = 32; o; o >>= 1) s += __shfl_xor(s, o);
  float mu = s * (1.0f/1024.0f);
  float vs = 0.f;
  #pragma unroll
  for (int i = 0; i < 4; i++) {
    float d0 = v[i].x-mu, d1 = v[i].y-mu, d2 = v[i].z-mu, d3 = v[i].w-mu;
    vs += d0*d0 + d1*d1 + d2*d2 + d3*d3;
  }
  #pragma unroll
  for (int o = 32; o; o >>= 1) vs += __shfl_xor(vs, o);
  float inv = 1.0f / sqrtf(vs*(1.0f/1024.0f) + 1e-5f);
  const float4* gp = (const float4*)g;
  const float4* bp = (const float4*)b;
  #pragma unroll
  for (int i = 0; i < 4; i++) {
    float4 gv = gp[lane+64*i], bv = bp[lane+64*i], o4;
    o4.x = (v[i].x-mu)*inv*gv.x + bv.x;
    o4.y = (v[i].y-mu)*inv*gv.y + bv.y;
    o4.z = (v[i].z-mu)*inv*gv.z + bv.z;
    o4.w = (v[i].w-mu)*inv*gv.w + bv.w;
    p[lane + 64*i] = o4;
  }
}

// ---------------- launch ----------------------------------------------------
extern "C" void kernel_launch(void* const* d_in, const int* in_sizes, int n_in,
                              void* d_out, int out_size, void* d_ws, size_t ws_size,
                              hipStream_t stream) {
  const float* x         = (const float*)d_in[0];
  const float* key_w     = (const float*)d_in[1];
  const float* out_w     = (const float*)d_in[2];
  const float* out_b     = (const float*)d_in[3];
  const float* gate_w    = (const float*)d_in[4];
  const float* gate_b    = (const float*)d_in[5];
  const float* ln_g      = (const float*)d_in[6];
  const float* ln_b      = (const float*)d_in[7];
  const float* pos_table = (const float*)d_in[8];
  const float* mem_keys  = (const float*)d_in[9];
  const float* mem_vals  = (const float*)d_in[10];
  const float* mem_age   = (const float*)d_in[11];
  const float* mem_conf  = (const float*)d_in[12];
  const int*   slot_order= (const int*)d_in[13];

  char* ws = (char*)d_ws;
  u16*   A    = (u16*)(ws + 0);            // combined bf16 [16384][2048]  64 MB
  u16*   Wcat = (u16*)(ws + 67108864);     // interleaved weights [2048][2048] 8 MB
  u16*   Wk   = (u16*)(ws + 75497472);     // key_w  bf16 [32][1024]       64 KB
  u16*   Vals = (u16*)(ws + 75563008);     // mem_vals bf16 [64][1024]    128 KB
  float* kwp  = (float*)(ws + 75694080);   // keys_with_pos [64][33]     8448 B
  float* biasv= (float*)(ws + 75702528);   // salience bias [64]
  float* qk   = (float*)(ws + 75702784);   // qk [16384][32] f32            2 MB
  float* y    = (float*)d_out;

  hipLaunchKernelGGL(k_prep,    dim3(1),    dim3(64),  0, stream,
                     mem_keys, pos_table, slot_order, mem_age, mem_conf, kwp, biasv);
  hipLaunchKernelGGL(k_convert, dim3(8192), dim3(256), 0, stream,
                     x, gate_w, out_w, key_w, mem_vals, A, Wcat, Wk, Vals);
  hipLaunchKernelGGL(k_qk,      dim3(256),  dim3(256), 0, stream, A, Wk, qk);
  hipLaunchKernelGGL(k_retr,    dim3(1024), dim3(256), 0, stream, qk, kwp, biasv, Vals, A);
  hipLaunchKernelGGL(k_gemm,    dim3(512),  dim3(512), 0, stream,
                     A, Wcat, x, out_b, gate_b, y);
  hipLaunchKernelGGL(k_ln,      dim3(4096), dim3(256), 0, stream, y, ln_g, ln_b);
}

// Round 4
// 280.726 us; speedup vs baseline: 1.1616x; 1.1616x over previous
//
#include <hip/hip_runtime.h>
#include <hip/hip_bf16.h>
#include <math.h>

// EpisodicMemory fused pipeline for MI355X (gfx950).
// B=16384, HID=1024, SLOTS=64, KD=32.
// Dominant cost: ONE [16384,2048]x[2048,2048] bf16 MFMA GEMM (gate/out weights
// row-interleaved in 16-col groups) with fused sigmoid/GELU/blend epilogue.
// k_gemm schedule: m201-style 4-phase/K-tile, BK=64, 256x256 tile, 8 waves,
// double-buffered LDS (128KB), counted vmcnt(2) (never drained in-loop),
// chunk-XOR LDS swizzle (inv-swizzled global src + swizzled ds_read),
// setprio(1) around each 16-MFMA cluster.

typedef float    f32x4 __attribute__((ext_vector_type(4)));
typedef short    s16x8 __attribute__((ext_vector_type(8)));
typedef unsigned short u16;
typedef unsigned short u16x8 __attribute__((ext_vector_type(8)));

#define MFMA_BF16(a,b,c) __builtin_amdgcn_mfma_f32_16x16x32_bf16((a),(b),(c),0,0,0)

__device__ __forceinline__ void async16(void* lds, const void* g) {
  __builtin_amdgcn_global_load_lds((const __attribute__((address_space(1))) void*)g,
                                   (__attribute__((address_space(3))) void*)lds, 16, 0, 0);
}

__device__ __forceinline__ u16 f2bf(float f) {
  unsigned u = __float_as_uint(f);
  u += 0x7fffu + ((u >> 16) & 1u);   // RNE
  return (u16)(u >> 16);
}
__device__ __forceinline__ float bf2f(u16 h) {
  return __uint_as_float(((unsigned)h) << 16);
}

// ---------------- K0: per-slot prep (keys_with_pos normalized, bias) --------
__global__ void k_prep(const float* __restrict__ mem_keys, const float* __restrict__ pos_table,
                       const int* __restrict__ slot_order, const float* __restrict__ mem_age,
                       const float* __restrict__ mem_conf,
                       float* __restrict__ kwp /*[64][33] padded*/, float* __restrict__ biasv) {
  int s = threadIdx.x;            // 64 threads = 1 wave
  float age  = mem_age[s];
  float freq = fmaxf(age, 1.0f);
  float fm = freq;
  #pragma unroll
  for (int o = 32; o; o >>= 1) fm = fmaxf(fm, __shfl_xor(fm, o));
  float freq_norm = logf(freq + 1.0f) / (logf(fm + 2.0f) + 1e-8f);
  float recency = expf(-age * (1.0f/200.0f));
  biasv[s] = 0.2f*recency + 0.15f*freq_norm + 0.1f*mem_conf[s] + 0.08f;

  int idx = slot_order[s] & 63;   // % SLOTS (values are arange, nonneg)
  float k[32]; float ss = 0.f;
  #pragma unroll
  for (int d = 0; d < 32; d++) {
    float v = mem_keys[s*32+d] + 0.1f*pos_table[idx*32+d];
    k[d] = v; ss += v*v;
  }
  float inv = 1.0f / fmaxf(sqrtf(ss), 1e-12f);
  #pragma unroll
  for (int d = 0; d < 32; d++) kwp[s*33+d] = k[d]*inv;
}

// ---------------- K1: fp32 -> bf16 conversions ------------------------------
// Weights go to Wcat [2048][2048]: row p = g*32 + h*16 + c holds
// (h==0 ? gate_w : out_w) row (g*16+c).
__global__ __launch_bounds__(256) void k_convert(
    const float* __restrict__ x, const float* __restrict__ gate_w,
    const float* __restrict__ out_w, const float* __restrict__ key_w,
    const float* __restrict__ mem_vals,
    u16* __restrict__ A, u16* __restrict__ Wcat,
    u16* __restrict__ Wk, u16* __restrict__ Vals) {
  const int NX = 4194304, NW = 524288, NK = 8192, NV = 16384;  // float4 groups
  const int total = NX + 2*NW + NK + NV;
  for (int g = blockIdx.x*256 + threadIdx.x; g < total; g += gridDim.x*256) {
    float4 v; u16* dst;
    if (g < NX) {                       // x -> combined[:, 0:1024]
      v = ((const float4*)x)[g];
      int r = g >> 8, c4 = g & 255;
      dst = A + ((size_t)r*2048 + c4*4);
    } else if (g < NX+NW) {             // gate_w -> Wcat interleaved
      int t = g-NX; v = ((const float4*)gate_w)[t];
      int row = t >> 9, grp = t & 511;
      int p = ((row>>4)<<5) + (row&15);
      dst = Wcat + ((size_t)p*2048 + grp*4);
    } else if (g < NX+2*NW) {           // out_w -> Wcat interleaved (+16)
      int t = g-NX-NW; v = ((const float4*)out_w)[t];
      int row = t >> 9, grp = t & 511;
      int p = ((row>>4)<<5) + 16 + (row&15);
      dst = Wcat + ((size_t)p*2048 + grp*4);
    } else if (g < NX+2*NW+NK) {
      int t = g-NX-2*NW; v = ((const float4*)key_w)[t];   dst = Wk + (size_t)t*4;
    } else {
      int t = g-NX-2*NW-NK; v = ((const float4*)mem_vals)[t]; dst = Vals + (size_t)t*4;
    }
    ushort4 o; o.x=f2bf(v.x); o.y=f2bf(v.y); o.z=f2bf(v.z); o.w=f2bf(v.w);
    *(ushort4*)dst = o;
  }
}

// ---------------- K2a: qk = x @ key_w^T  (thin MFMA GEMM) -------------------
__global__ __launch_bounds__(256) void k_qk(const u16* __restrict__ A, const u16* __restrict__ Wk,
                                            float* __restrict__ qk) {
  __shared__ __align__(16) u16 sA[64*64];
  __shared__ __align__(16) u16 sB[32*64];
  int tid = threadIdx.x, lane = tid & 63, w = tid >> 6;
  int r0 = blockIdx.x * 64;
  f32x4 acc[2] = { {0.f,0.f,0.f,0.f}, {0.f,0.f,0.f,0.f} };
  for (int k0 = 0; k0 < 1024; k0 += 64) {
    const char* Ab = (const char*)A + ((size_t)r0*2048 + k0)*2;   // A row stride 4096 B
    #pragma unroll
    for (int i = 0; i < 2; i++) {
      int cidx = tid + i*256;                  // 512 chunks of 16 B
      async16((char*)sA + cidx*16, Ab + (size_t)(cidx>>3)*4096 + (size_t)(cidx&7)*16);
    }
    { const char* Bb = (const char*)Wk + (size_t)k0*2;            // Wk row stride 2048 B
      async16((char*)sB + tid*16, Bb + (size_t)(tid>>3)*2048 + (size_t)(tid&7)*16); }
    __syncthreads();
    #pragma unroll
    for (int kk = 0; kk < 2; kk++) {
      int kb = kk*32 + (lane>>4)*8;
      s16x8 a  = *(const s16x8*)&sA[(w*16 + (lane&15))*64 + kb];
      s16x8 b0 = *(const s16x8*)&sB[(lane&15)*64 + kb];
      s16x8 b1 = *(const s16x8*)&sB[((lane&15)+16)*64 + kb];
      acc[0] = MFMA_BF16(a, b0, acc[0]);
      acc[1] = MFMA_BF16(a, b1, acc[1]);
    }
    __syncthreads();
  }
  int rr = (lane>>4)*4, cc = lane&15;
  #pragma unroll
  for (int n = 0; n < 2; n++)
    #pragma unroll
    for (int i = 0; i < 4; i++)
      qk[(size_t)(r0 + w*16 + rr + i)*32 + n*16 + cc] = acc[n][i];
}

// ---------------- K2b: softmax over slots + retrieved = attn @ mem_vals -----
__global__ __launch_bounds__(256) void k_retr(const float* __restrict__ qk,
                                              const float* __restrict__ kwp,
                                              const float* __restrict__ biasv,
                                              const u16* __restrict__ Vals,
                                              u16* __restrict__ A) {
  __shared__ float sK[64*33];
  __shared__ float sBias[64];
  __shared__ float sQn[16*32];
  __shared__ float sAttn[16*64];
  int tid = threadIdx.x, lane = tid & 63, w = tid >> 6;
  int row0 = blockIdx.x * 16;
  for (int i = tid; i < 64*33; i += 256) sK[i] = kwp[i];
  if (tid < 64) sBias[tid] = biasv[tid];
  __syncthreads();

  int d = lane & 31;
  for (int j = 0; j < 4; j++) {
    int rl = w*4 + j;
    float v = qk[(size_t)(row0+rl)*32 + d];
    float sq = v*v;
    #pragma unroll
    for (int o = 16; o; o >>= 1) sq += __shfl_xor(sq, o);   // 32-lane group sum
    float qn = v / fmaxf(sqrtf(sq), 1e-12f);
    if (lane < 32) sQn[rl*32 + d] = qn;
    float accs = 0.f;
    #pragma unroll
    for (int dd = 0; dd < 32; dd++) accs += sK[lane*33+dd] * sQn[rl*32+dd];
    float sim = accs * 0.17677669529663687f;   // 1/sqrt(32)
    float sal = fminf(fmaxf(0.45f*sim + sBias[lane], 0.0f), 1.0f);
    float mx = sal;
    #pragma unroll
    for (int o = 32; o; o >>= 1) mx = fmaxf(mx, __shfl_xor(mx, o));
    float e = expf(sal - mx);
    float sm = e;
    #pragma unroll
    for (int o = 32; o; o >>= 1) sm += __shfl_xor(sm, o);
    sAttn[rl*64 + lane] = e / sm;
  }
  __syncthreads();

  float acc[4][16];
  #pragma unroll
  for (int j = 0; j < 4; j++)
    #pragma unroll
    for (int i = 0; i < 16; i++) acc[j][i] = 0.f;
  const u16* vp = Vals + lane*16;
  for (int s = 0; s < 64; s++) {
    s16x8 v0 = *(const s16x8*)(vp + (size_t)s*1024);
    s16x8 v1 = *(const s16x8*)(vp + (size_t)s*1024 + 8);
    float vf[16];
    #pragma unroll
    for (int i = 0; i < 8; i++) { vf[i] = bf2f((u16)v0[i]); vf[8+i] = bf2f((u16)v1[i]); }
    #pragma unroll
    for (int j = 0; j < 4; j++) {
      float a = sAttn[(w*4+j)*64 + s];
      #pragma unroll
      for (int i = 0; i < 16; i++) acc[j][i] += a * vf[i];
    }
  }
  #pragma unroll
  for (int j = 0; j < 4; j++) {
    int r = row0 + w*4 + j;
    u16x8 o0, o1;
    #pragma unroll
    for (int i = 0; i < 8; i++) { o0[i] = f2bf(acc[j][i]); o1[i] = f2bf(acc[j][8+i]); }
    u16* dst = A + (size_t)r*2048 + 1024 + lane*16;   // combined[:, 1024:2048]
    *(u16x8*)dst = o0;
    *(u16x8*)(dst + 8) = o1;
  }
}

// ---------------- K3: single interleaved GEMM + fused epilogue --------------
// C = combined[16384,2048] @ Wcat[2048,2048]^T.
// 256x256 tile, BK=64, 8 waves (2M x 4N), split-strip ownership:
//   wave wm owns rows {wm*64..+63} u {128+wm*64..+63}
//   wave wn owns Wcat-rows {wn*32..+31} u {128+wn*32..+31}
// 4 phases per K-tile: (strip0,k0) (strip1,k0) (strip0,k1) (strip1,k1),
// per phase: 4-8 ds_read_b128 + 1 half-tile stage + 16 MFMA, 2 barriers.
// Tile u+1 staged during tile u into the other (fully consumed) buffer.
// vmcnt(2) at phase-0-end and phase-3-end only (counted, never drained).
__global__ __launch_bounds__(512, 2) void k_gemm(
    const u16* __restrict__ A, const u16* __restrict__ Wcat,
    const float* __restrict__ x, const float* __restrict__ out_b,
    const float* __restrict__ gate_b, float* __restrict__ y) {
  __shared__ __align__(16) u16 sA[2][16384];   // 2 x 256rows x 64K (32 KB)
  __shared__ __align__(16) u16 sB[2][16384];

  const int tid = threadIdx.x, lane = tid & 63;
  const int w = tid >> 6;
  const int ln15 = lane & 15, hi = lane >> 4;
  const int wm = w >> 2, wn = w & 3;

  const int colblk = blockIdx.x & 7;   // XCD-resident weight panel
  const int rowblk = blockIdx.x >> 3;
  const size_t r0 = (size_t)rowblk * 256;
  const size_t c0 = (size_t)colblk * 256;

  const u16* gA = A    + r0 * 2048;
  const u16* gB = Wcat + c0 * 2048;

  // staging: half-tile = 128 rows x 64 cols = 1024 chunks of 16B; 2/thread.
  // physical chunk pc holds logical chunk pc ^ (row&7)  (inv-swz on source).
  const int i0 = tid, i1 = tid + 512;
  const int sr0 = i0 >> 3, sl0 = (i0 & 7) ^ (sr0 & 7);
  const int sr1 = i1 >> 3, sl1 = (i1 & 7) ^ (sr1 & 7);

  #define STAGE_A(b, kt, s) do {                                              \
    async16(&sA[b][(s)*8192 + i0*8], gA + (size_t)((s)*128 + sr0)*2048 + (kt)*64 + sl0*8); \
    async16(&sA[b][(s)*8192 + i1*8], gA + (size_t)((s)*128 + sr1)*2048 + (kt)*64 + sl1*8); \
  } while (0)
  #define STAGE_B(b, kt, s) do {                                              \
    async16(&sB[b][(s)*8192 + i0*8], gB + (size_t)((s)*128 + sr0)*2048 + (kt)*64 + sl0*8); \
    async16(&sB[b][(s)*8192 + i1*8], gB + (size_t)((s)*128 + sr1)*2048 + (kt)*64 + sl1*8); \
  } while (0)

  // ds_read addressing (swizzled chunk): pc = ((kh*4+hi) ^ (ln15&7))
  const int p7  = ln15 & 7;
  const int ck0 = (hi ^ p7) * 8;          // kh=0
  const int ck1 = ((4 | hi) ^ p7) * 8;    // kh=1
  const int arow = (wm*64 + ln15) * 64;   // + m*1024 + strip*8192
  const int brow = (wn*32 + ln15) * 64;   // + (n&1)*1024 + (n>>1)*8192

  f32x4 acc[8][4];
  #pragma unroll
  for (int m = 0; m < 8; m++)
    #pragma unroll
    for (int n = 0; n < 4; n++) acc[m][n] = {0.f, 0.f, 0.f, 0.f};

  // prologue: tile 0, stage order Al, Bl, Bh, Ah
  STAGE_A(0, 0, 0);
  STAGE_B(0, 0, 0);
  STAGE_B(0, 0, 1);
  STAGE_A(0, 0, 1);
  asm volatile("s_waitcnt vmcnt(2)" ::: "memory");   // Al,Bl,Bh landed; Ah in flight
  __builtin_amdgcn_s_barrier();

  #pragma unroll 1
  for (int u = 0; u < 32; ++u) {
    const int b = u & 1, nb = b ^ 1;
    const bool more = (u + 1 < 32);
    const u16* sa = sA[b];
    const u16* sb = sB[b];
    s16x8 av[4], bk[4];

    // ---- phase 0: (strip0, kh0); stage Al(u+1) ----
    #pragma unroll
    for (int m = 0; m < 4; m++) av[m] = *(const s16x8*)&sa[arow + m*1024 + ck0];
    #pragma unroll
    for (int n = 0; n < 4; n++) bk[n] = *(const s16x8*)&sb[(n>>1)*8192 + brow + (n&1)*1024 + ck0];
    if (more) STAGE_A(nb, u+1, 0);
    __builtin_amdgcn_s_barrier();
    asm volatile("" ::: "memory");
    __builtin_amdgcn_s_setprio(1);
    #pragma unroll
    for (int m = 0; m < 4; m++)
      #pragma unroll
      for (int n = 0; n < 4; n++) acc[m][n] = MFMA_BF16(av[m], bk[n], acc[m][n]);
    __builtin_amdgcn_s_setprio(0);
    if (more) asm volatile("s_waitcnt vmcnt(2)" ::: "memory");  // Ah(u) landed
    else      asm volatile("s_waitcnt vmcnt(0)" ::: "memory");
    __builtin_amdgcn_s_barrier();

    // ---- phase 1: (strip1, kh0); stage Bl(u+1); reuse bk ----
    #pragma unroll
    for (int m = 0; m < 4; m++) av[m] = *(const s16x8*)&sa[8192 + arow + m*1024 + ck0];
    if (more) STAGE_B(nb, u+1, 0);
    __builtin_amdgcn_s_barrier();
    asm volatile("" ::: "memory");
    __builtin_amdgcn_s_setprio(1);
    #pragma unroll
    for (int m = 0; m < 4; m++)
      #pragma unroll
      for (int n = 0; n < 4; n++) acc[4+m][n] = MFMA_BF16(av[m], bk[n], acc[4+m][n]);
    __builtin_amdgcn_s_setprio(0);
    __builtin_amdgcn_s_barrier();

    // ---- phase 2: (strip0, kh1); stage Bh(u+1) ----
    #pragma unroll
    for (int m = 0; m < 4; m++) av[m] = *(const s16x8*)&sa[arow + m*1024 + ck1];
    #pragma unroll
    for (int n = 0; n < 4; n++) bk[n] = *(const s16x8*)&sb[(n>>1)*8192 + brow + (n&1)*1024 + ck1];
    if (more) STAGE_B(nb, u+1, 1);
    __builtin_amdgcn_s_barrier();
    asm volatile("" ::: "memory");
    __builtin_amdgcn_s_setprio(1);
    #pragma unroll
    for (int m = 0; m < 4; m++)
      #pragma unroll
      for (int n = 0; n < 4; n++) acc[m][n] = MFMA_BF16(av[m], bk[n], acc[m][n]);
    __builtin_amdgcn_s_setprio(0);
    __builtin_amdgcn_s_barrier();

    // ---- phase 3: (strip1, kh1); stage Ah(u+1) ----
    #pragma unroll
    for (int m = 0; m < 4; m++) av[m] = *(const s16x8*)&sa[8192 + arow + m*1024 + ck1];
    if (more) STAGE_A(nb, u+1, 1);
    __builtin_amdgcn_s_barrier();
    asm volatile("" ::: "memory");
    __builtin_amdgcn_s_setprio(1);
    #pragma unroll
    for (int m = 0; m < 4; m++)
      #pragma unroll
      for (int n = 0; n < 4; n++) acc[4+m][n] = MFMA_BF16(av[m], bk[n], acc[4+m][n]);
    __builtin_amdgcn_s_setprio(0);
    if (more) asm volatile("s_waitcnt vmcnt(2)" ::: "memory");  // Al,Bl,Bh(u+1) landed
    __builtin_amdgcn_s_barrier();
  }
  #undef STAGE_A
  #undef STAGE_B

  // epilogue: acc[m][2s]=gate, acc[m][2s+1]=out for ocol below; y pre-LN
  #pragma unroll
  for (int s = 0; s < 2; s++) {
    int ocol = colblk*128 + s*64 + wn*16 + ln15;
    float gbv = gate_b[ocol], obv = out_b[ocol];
    #pragma unroll
    for (int m = 0; m < 8; m++) {
      #pragma unroll
      for (int i = 0; i < 4; i++) {
        size_t r = r0 + (m>>2)*128 + wm*64 + (m&3)*16 + hi*4 + i;
        float gg = acc[m][s*2+0][i] + gbv;
        float go = acc[m][s*2+1][i] + obv;
        float h  = 0.5f*go*(1.0f + erff(go*0.70710678118654752f));  // exact gelu
        float sg = 1.0f/(1.0f + __expf(-gg));
        float rv = bf2f(A[r*2048 + 1024 + ocol]);
        float xv = x[r*1024 + ocol];
        y[r*1024 + ocol] = h + sg*rv + (1.0f - sg)*xv;
      }
    }
  }
}

// ---------------- K4: LayerNorm in place (wave per row) ---------------------
__global__ __launch_bounds__(256) void k_ln(float* __restrict__ y, const float* __restrict__ g,
                                            const float* __restrict__ b) {
  int row  = blockIdx.x*4 + (threadIdx.x >> 6);
  int lane = threadIdx.x & 63;
  float4* p = (float4*)(y + (size_t)row*1024);
  float4 v[4];
  #pragma unroll
  for (int i = 0; i < 4; i++) v[i] = p[lane + 64*i];
  float s = 0.f;
  #pragma unroll
  for (int i = 0; i < 4; i++) s += v[i].x + v[i].y + v[i].z + v[i].w;
  #pragma unroll
  for (int o = 32; o; o >>= 1) s += __shfl_xor(s, o);
  float mu = s * (1.0f/1024.0f);
  float vs = 0.f;
  #pragma unroll
  for (int i = 0; i < 4; i++) {
    float d0 = v[i].x-mu, d1 = v[i].y-mu, d2 = v[i].z-mu, d3 = v[i].w-mu;
    vs += d0*d0 + d1*d1 + d2*d2 + d3*d3;
  }
  #pragma unroll
  for (int o = 32; o; o >>= 1) vs += __shfl_xor(vs, o);
  float inv = 1.0f / sqrtf(vs*(1.0f/1024.0f) + 1e-5f);
  const float4* gp = (const float4*)g;
  const float4* bp = (const float4*)b;
  #pragma unroll
  for (int i = 0; i < 4; i++) {
    float4 gv = gp[lane+64*i], bv = bp[lane+64*i], o4;
    o4.x = (v[i].x-mu)*inv*gv.x + bv.x;
    o4.y = (v[i].y-mu)*inv*gv.y + bv.y;
    o4.z = (v[i].z-mu)*inv*gv.z + bv.z;
    o4.w = (v[i].w-mu)*inv*gv.w + bv.w;
    p[lane + 64*i] = o4;
  }
}

// ---------------- launch ----------------------------------------------------
extern "C" void kernel_launch(void* const* d_in, const int* in_sizes, int n_in,
                              void* d_out, int out_size, void* d_ws, size_t ws_size,
                              hipStream_t stream) {
  const float* x         = (const float*)d_in[0];
  const float* key_w     = (const float*)d_in[1];
  const float* out_w     = (const float*)d_in[2];
  const float* out_b     = (const float*)d_in[3];
  const float* gate_w    = (const float*)d_in[4];
  const float* gate_b    = (const float*)d_in[5];
  const float* ln_g      = (const float*)d_in[6];
  const float* ln_b      = (const float*)d_in[7];
  const float* pos_table = (const float*)d_in[8];
  const float* mem_keys  = (const float*)d_in[9];
  const float* mem_vals  = (const float*)d_in[10];
  const float* mem_age   = (const float*)d_in[11];
  const float* mem_conf  = (const float*)d_in[12];
  const int*   slot_order= (const int*)d_in[13];

  char* ws = (char*)d_ws;
  u16*   A    = (u16*)(ws + 0);            // combined bf16 [16384][2048]  64 MB
  u16*   Wcat = (u16*)(ws + 67108864);     // interleaved weights [2048][2048] 8 MB
  u16*   Wk   = (u16*)(ws + 75497472);     // key_w  bf16 [32][1024]       64 KB
  u16*   Vals = (u16*)(ws + 75563008);     // mem_vals bf16 [64][1024]    128 KB
  float* kwp  = (float*)(ws + 75694080);   // keys_with_pos [64][33]     8448 B
  float* biasv= (float*)(ws + 75702528);   // salience bias [64]
  float* qk   = (float*)(ws + 75702784);   // qk [16384][32] f32            2 MB
  float* y    = (float*)d_out;

  hipLaunchKernelGGL(k_prep,    dim3(1),    dim3(64),  0, stream,
                     mem_keys, pos_table, slot_order, mem_age, mem_conf, kwp, biasv);
  hipLaunchKernelGGL(k_convert, dim3(8192), dim3(256), 0, stream,
                     x, gate_w, out_w, key_w, mem_vals, A, Wcat, Wk, Vals);
  hipLaunchKernelGGL(k_qk,      dim3(256),  dim3(256), 0, stream, A, Wk, qk);
  hipLaunchKernelGGL(k_retr,    dim3(1024), dim3(256), 0, stream, qk, kwp, biasv, Vals, A);
  hipLaunchKernelGGL(k_gemm,    dim3(512),  dim3(512), 0, stream,
                     A, Wcat, x, out_b, gate_b, y);
  hipLaunchKernelGGL(k_ln,      dim3(4096), dim3(256), 0, stream, y, ln_g, ln_b);
}

// Round 5
// 280.276 us; speedup vs baseline: 1.1635x; 1.0016x over previous
//
#include <hip/hip_runtime.h>
#include <hip/hip_bf16.h>
#include <math.h>

// EpisodicMemory fused pipeline for MI355X (gfx950).
// B=16384, HID=1024, SLOTS=64, KD=32.
// Dominant cost: ONE [16384,2048]x[2048,2048] bf16 MFMA GEMM (gate/out weights
// row-interleaved in 16-col groups) with fused sigmoid/GELU/blend epilogue.
// k_gemm: m201-faithful 8-phase / 2-K-tile iteration, BK=64, 256x256 tile,
// 8 waves (2Mx4N), double-buffered LDS (128KB), ONE stage-op per phase,
// counted vmcnt(2) at phases 4 & 8 only, chunk-XOR LDS swizzle, setprio.

typedef float    f32x4 __attribute__((ext_vector_type(4)));
typedef short    s16x8 __attribute__((ext_vector_type(8)));
typedef unsigned short u16;
typedef unsigned short u16x8 __attribute__((ext_vector_type(8)));

#define MFMA_BF16(a,b,c) __builtin_amdgcn_mfma_f32_16x16x32_bf16((a),(b),(c),0,0,0)

__device__ __forceinline__ void async16(void* lds, const void* g) {
  __builtin_amdgcn_global_load_lds((const __attribute__((address_space(1))) void*)g,
                                   (__attribute__((address_space(3))) void*)lds, 16, 0, 0);
}

__device__ __forceinline__ u16 f2bf(float f) {
  unsigned u = __float_as_uint(f);
  u += 0x7fffu + ((u >> 16) & 1u);   // RNE
  return (u16)(u >> 16);
}
__device__ __forceinline__ float bf2f(u16 h) {
  return __uint_as_float(((unsigned)h) << 16);
}

// ---------------- K0: per-slot prep (keys_with_pos normalized, bias) --------
__global__ void k_prep(const float* __restrict__ mem_keys, const float* __restrict__ pos_table,
                       const int* __restrict__ slot_order, const float* __restrict__ mem_age,
                       const float* __restrict__ mem_conf,
                       float* __restrict__ kwp /*[64][33] padded*/, float* __restrict__ biasv) {
  int s = threadIdx.x;            // 64 threads = 1 wave
  float age  = mem_age[s];
  float freq = fmaxf(age, 1.0f);
  float fm = freq;
  #pragma unroll
  for (int o = 32; o; o >>= 1) fm = fmaxf(fm, __shfl_xor(fm, o));
  float freq_norm = logf(freq + 1.0f) / (logf(fm + 2.0f) + 1e-8f);
  float recency = expf(-age * (1.0f/200.0f));
  biasv[s] = 0.2f*recency + 0.15f*freq_norm + 0.1f*mem_conf[s] + 0.08f;

  int idx = slot_order[s] & 63;   // % SLOTS (values are arange, nonneg)
  float k[32]; float ss = 0.f;
  #pragma unroll
  for (int d = 0; d < 32; d++) {
    float v = mem_keys[s*32+d] + 0.1f*pos_table[idx*32+d];
    k[d] = v; ss += v*v;
  }
  float inv = 1.0f / fmaxf(sqrtf(ss), 1e-12f);
  #pragma unroll
  for (int d = 0; d < 32; d++) kwp[s*33+d] = k[d]*inv;
}

// ---------------- K1: fp32 -> bf16 conversions ------------------------------
// Weights go to Wcat [2048][2048]: row p = g*32 + h*16 + c holds
// (h==0 ? gate_w : out_w) row (g*16+c).
__global__ __launch_bounds__(256) void k_convert(
    const float* __restrict__ x, const float* __restrict__ gate_w,
    const float* __restrict__ out_w, const float* __restrict__ key_w,
    const float* __restrict__ mem_vals,
    u16* __restrict__ A, u16* __restrict__ Wcat,
    u16* __restrict__ Wk, u16* __restrict__ Vals) {
  const int NX = 4194304, NW = 524288, NK = 8192, NV = 16384;  // float4 groups
  const int total = NX + 2*NW + NK + NV;
  for (int g = blockIdx.x*256 + threadIdx.x; g < total; g += gridDim.x*256) {
    float4 v; u16* dst;
    if (g < NX) {                       // x -> combined[:, 0:1024]
      v = ((const float4*)x)[g];
      int r = g >> 8, c4 = g & 255;
      dst = A + ((size_t)r*2048 + c4*4);
    } else if (g < NX+NW) {             // gate_w -> Wcat interleaved
      int t = g-NX; v = ((const float4*)gate_w)[t];
      int row = t >> 9, grp = t & 511;
      int p = ((row>>4)<<5) + (row&15);
      dst = Wcat + ((size_t)p*2048 + grp*4);
    } else if (g < NX+2*NW) {           // out_w -> Wcat interleaved (+16)
      int t = g-NX-NW; v = ((const float4*)out_w)[t];
      int row = t >> 9, grp = t & 511;
      int p = ((row>>4)<<5) + 16 + (row&15);
      dst = Wcat + ((size_t)p*2048 + grp*4);
    } else if (g < NX+2*NW+NK) {
      int t = g-NX-2*NW; v = ((const float4*)key_w)[t];   dst = Wk + (size_t)t*4;
    } else {
      int t = g-NX-2*NW-NK; v = ((const float4*)mem_vals)[t]; dst = Vals + (size_t)t*4;
    }
    ushort4 o; o.x=f2bf(v.x); o.y=f2bf(v.y); o.z=f2bf(v.z); o.w=f2bf(v.w);
    *(ushort4*)dst = o;
  }
}

// ---------------- K2a: qk = x @ key_w^T  (thin MFMA GEMM) -------------------
__global__ __launch_bounds__(256) void k_qk(const u16* __restrict__ A, const u16* __restrict__ Wk,
                                            float* __restrict__ qk) {
  __shared__ __align__(16) u16 sA[64*64];
  __shared__ __align__(16) u16 sB[32*64];
  int tid = threadIdx.x, lane = tid & 63, w = tid >> 6;
  int r0 = blockIdx.x * 64;
  f32x4 acc[2] = { {0.f,0.f,0.f,0.f}, {0.f,0.f,0.f,0.f} };
  for (int k0 = 0; k0 < 1024; k0 += 64) {
    const char* Ab = (const char*)A + ((size_t)r0*2048 + k0)*2;   // A row stride 4096 B
    #pragma unroll
    for (int i = 0; i < 2; i++) {
      int cidx = tid + i*256;                  // 512 chunks of 16 B
      async16((char*)sA + cidx*16, Ab + (size_t)(cidx>>3)*4096 + (size_t)(cidx&7)*16);
    }
    { const char* Bb = (const char*)Wk + (size_t)k0*2;            // Wk row stride 2048 B
      async16((char*)sB + tid*16, Bb + (size_t)(tid>>3)*2048 + (size_t)(tid&7)*16); }
    __syncthreads();
    #pragma unroll
    for (int kk = 0; kk < 2; kk++) {
      int kb = kk*32 + (lane>>4)*8;
      s16x8 a  = *(const s16x8*)&sA[(w*16 + (lane&15))*64 + kb];
      s16x8 b0 = *(const s16x8*)&sB[(lane&15)*64 + kb];
      s16x8 b1 = *(const s16x8*)&sB[((lane&15)+16)*64 + kb];
      acc[0] = MFMA_BF16(a, b0, acc[0]);
      acc[1] = MFMA_BF16(a, b1, acc[1]);
    }
    __syncthreads();
  }
  int rr = (lane>>4)*4, cc = lane&15;
  #pragma unroll
  for (int n = 0; n < 2; n++)
    #pragma unroll
    for (int i = 0; i < 4; i++)
      qk[(size_t)(r0 + w*16 + rr + i)*32 + n*16 + cc] = acc[n][i];
}

// ---------------- K2b: softmax over slots + retrieved = attn @ mem_vals -----
__global__ __launch_bounds__(256) void k_retr(const float* __restrict__ qk,
                                              const float* __restrict__ kwp,
                                              const float* __restrict__ biasv,
                                              const u16* __restrict__ Vals,
                                              u16* __restrict__ A) {
  __shared__ float sK[64*33];
  __shared__ float sBias[64];
  __shared__ float sQn[16*32];
  __shared__ float sAttn[16*64];
  int tid = threadIdx.x, lane = tid & 63, w = tid >> 6;
  int row0 = blockIdx.x * 16;
  for (int i = tid; i < 64*33; i += 256) sK[i] = kwp[i];
  if (tid < 64) sBias[tid] = biasv[tid];
  __syncthreads();

  int d = lane & 31;
  for (int j = 0; j < 4; j++) {
    int rl = w*4 + j;
    float v = qk[(size_t)(row0+rl)*32 + d];
    float sq = v*v;
    #pragma unroll
    for (int o = 16; o; o >>= 1) sq += __shfl_xor(sq, o);   // 32-lane group sum
    float qn = v / fmaxf(sqrtf(sq), 1e-12f);
    if (lane < 32) sQn[rl*32 + d] = qn;
    float accs = 0.f;
    #pragma unroll
    for (int dd = 0; dd < 32; dd++) accs += sK[lane*33+dd] * sQn[rl*32+dd];
    float sim = accs * 0.17677669529663687f;   // 1/sqrt(32)
    float sal = fminf(fmaxf(0.45f*sim + sBias[lane], 0.0f), 1.0f);
    float mx = sal;
    #pragma unroll
    for (int o = 32; o; o >>= 1) mx = fmaxf(mx, __shfl_xor(mx, o));
    float e = expf(sal - mx);
    float sm = e;
    #pragma unroll
    for (int o = 32; o; o >>= 1) sm += __shfl_xor(sm, o);
    sAttn[rl*64 + lane] = e / sm;
  }
  __syncthreads();

  float acc[4][16];
  #pragma unroll
  for (int j = 0; j < 4; j++)
    #pragma unroll
    for (int i = 0; i < 16; i++) acc[j][i] = 0.f;
  const u16* vp = Vals + lane*16;
  for (int s = 0; s < 64; s++) {
    s16x8 v0 = *(const s16x8*)(vp + (size_t)s*1024);
    s16x8 v1 = *(const s16x8*)(vp + (size_t)s*1024 + 8);
    float vf[16];
    #pragma unroll
    for (int i = 0; i < 8; i++) { vf[i] = bf2f((u16)v0[i]); vf[8+i] = bf2f((u16)v1[i]); }
    #pragma unroll
    for (int j = 0; j < 4; j++) {
      float a = sAttn[(w*4+j)*64 + s];
      #pragma unroll
      for (int i = 0; i < 16; i++) acc[j][i] += a * vf[i];
    }
  }
  #pragma unroll
  for (int j = 0; j < 4; j++) {
    int r = row0 + w*4 + j;
    u16x8 o0, o1;
    #pragma unroll
    for (int i = 0; i < 8; i++) { o0[i] = f2bf(acc[j][i]); o1[i] = f2bf(acc[j][8+i]); }
    u16* dst = A + (size_t)r*2048 + 1024 + lane*16;   // combined[:, 1024:2048]
    *(u16x8*)dst = o0;
    *(u16x8*)(dst + 8) = o1;
  }
}

// ---------------- K3: single interleaved GEMM + fused epilogue --------------
// C = combined[16384,2048] @ Wcat[2048,2048]^T.
// 256x256 tile, 8 waves (2M x 4N), per-wave 128x64 output.
// Iteration = 2 K-tiles (BK=64 each, buf0/buf1), 8 phases, quadrant order
// q00,q01,q11,q10 per K-tile (reads 12/4/8/4 x ds_read_b128, single A/B
// register sets). One stage-op (2 global_load_lds) per phase; stage order:
//   P1:A(t1,h1) P2:B(t1,h0) P3:B(t1,h1) P4:A(t2,h0)
//   P5:A(t2,h1) P6:B(t2,h0) P7:B(t2,h1) P8:A(t3,h0)
// vmcnt(2) at P4 & P8 ends only (A leads 3-4 phases; B 1-2, L2-resident).
__global__ __launch_bounds__(512, 2) void k_gemm(
    const u16* __restrict__ A, const u16* __restrict__ Wcat,
    const float* __restrict__ x, const float* __restrict__ out_b,
    const float* __restrict__ gate_b, float* __restrict__ y) {
  __shared__ __align__(16) u16 sA[2][16384];   // [buf][half*8192 + row*64 + swz]
  __shared__ __align__(16) u16 sB[2][16384];

  const int tid = threadIdx.x, lane = tid & 63;
  const int w = tid >> 6;
  const int ln15 = lane & 15, hi = lane >> 4;
  const int wm = w >> 2, wn = w & 3;
  const int p7 = ln15 & 7;

  const int colblk = blockIdx.x & 7;   // XCD-resident weight panel
  const int rowblk = blockIdx.x >> 3;
  const size_t r0 = (size_t)rowblk * 256;
  const size_t c0 = (size_t)colblk * 256;

  const u16* gA = A    + r0 * 2048;
  const u16* gB = Wcat + c0 * 2048;

  // staging: half-tile = 128 rows x 64 cols; 1024 chunks of 16B, 2/thread.
  // physical chunk pc of row r holds logical chunk pc ^ (r&7).
  const int i0 = tid, i1 = tid + 512;
  const int sr0 = i0 >> 3, sl0 = (i0 & 7) ^ (sr0 & 7);
  const int sr1 = i1 >> 3, sl1 = (i1 & 7) ^ (sr1 & 7);
  const u16* a0p = gA + (size_t)sr0*2048 + sl0*8;   // + h*262144 + kt*64
  const u16* a1p = gA + (size_t)sr1*2048 + sl1*8;
  const u16* b0p = gB + (size_t)sr0*2048 + sl0*8;
  const u16* b1p = gB + (size_t)sr1*2048 + sl1*8;

  #define STAGE_A(buf, kt, h) do {                                            \
    async16(&sA[buf][(h)*8192 + i0*8], a0p + (size_t)(h)*262144 + (kt)*64);   \
    async16(&sA[buf][(h)*8192 + i1*8], a1p + (size_t)(h)*262144 + (kt)*64);   \
  } while (0)
  #define STAGE_B(buf, kt, h) do {                                            \
    async16(&sB[buf][(h)*8192 + i0*8], b0p + (size_t)(h)*262144 + (kt)*64);   \
    async16(&sB[buf][(h)*8192 + i1*8], b1p + (size_t)(h)*262144 + (kt)*64);   \
  } while (0)

  // ds_read addressing: logical chunk lc -> physical (lc ^ (row&7)); row&7=p7.
  const int c0k = (hi ^ p7) * 8;          // kk=0: lc = hi
  const int c1k = ((4 | hi) ^ p7) * 8;    // kk=1: lc = 4|hi
  const int arow = (wm*64 + ln15) * 64;   // + m*1024 + mh*8192
  const int brow = (wn*32 + ln15) * 64;   // + n2*1024 + nh*8192

  s16x8 aset[4][2], bset[2][2];
  #define LOAD_A(buf, mh) do {                                                \
    _Pragma("unroll")                                                         \
    for (int m = 0; m < 4; m++) {                                             \
      aset[m][0] = *(const s16x8*)&sA[buf][(mh)*8192 + arow + m*1024 + c0k];  \
      aset[m][1] = *(const s16x8*)&sA[buf][(mh)*8192 + arow + m*1024 + c1k];  \
    }                                                                         \
  } while (0)
  #define LOAD_B(buf, nh) do {                                                \
    _Pragma("unroll")                                                         \
    for (int n2 = 0; n2 < 2; n2++) {                                          \
      bset[n2][0] = *(const s16x8*)&sB[buf][(nh)*8192 + brow + n2*1024 + c0k];\
      bset[n2][1] = *(const s16x8*)&sB[buf][(nh)*8192 + brow + n2*1024 + c1k];\
    }                                                                         \
  } while (0)

  f32x4 acc[2][4][4];
  #pragma unroll
  for (int mh = 0; mh < 2; mh++)
    #pragma unroll
    for (int m = 0; m < 4; m++)
      #pragma unroll
      for (int n = 0; n < 4; n++) acc[mh][m][n] = {0.f, 0.f, 0.f, 0.f};

  #define MFMA_Q(mh, nh) do {                                                 \
    __builtin_amdgcn_s_setprio(1);                                            \
    _Pragma("unroll")                                                         \
    for (int m = 0; m < 4; m++)                                               \
      _Pragma("unroll")                                                       \
      for (int n2 = 0; n2 < 2; n2++) {                                        \
        acc[mh][m][(nh)*2+n2] = MFMA_BF16(aset[m][0], bset[n2][0], acc[mh][m][(nh)*2+n2]); \
        acc[mh][m][(nh)*2+n2] = MFMA_BF16(aset[m][1], bset[n2][1], acc[mh][m][(nh)*2+n2]); \
      }                                                                       \
    __builtin_amdgcn_s_setprio(0);                                            \
  } while (0)

  #define BAR() __builtin_amdgcn_s_barrier()
  #define FENCE() asm volatile("" ::: "memory")

  // prologue: t0 -> buf0 (4 ops), t1 A-h0 -> buf1 (1 op); gate t0 complete
  STAGE_A(0, 0, 0);
  STAGE_A(0, 0, 1);
  STAGE_B(0, 0, 0);
  STAGE_B(0, 0, 1);
  STAGE_A(1, 1, 0);
  asm volatile("s_waitcnt vmcnt(2)" ::: "memory");
  BAR();

  #pragma unroll 1
  for (int i = 0; i < 16; ++i) {
    const bool more = (i < 15);
    const int kt1 = 2*i + 1, kt2 = 2*i + 2, kt3 = 2*i + 3;

    // P1: q00(buf0)
    LOAD_A(0, 0); LOAD_B(0, 0);
    STAGE_A(1, kt1, 1);
    BAR(); FENCE();
    MFMA_Q(0, 0);
    BAR();
    // P2: q01(buf0), keep aset
    LOAD_B(0, 1);
    STAGE_B(1, kt1, 0);
    BAR(); FENCE();
    MFMA_Q(0, 1);
    BAR();
    // P3: q11(buf0), keep bset
    LOAD_A(0, 1);
    STAGE_B(1, kt1, 1);
    BAR(); FENCE();
    MFMA_Q(1, 1);
    BAR();
    // P4: q10(buf0); gate: t1 fully landed, A(t2,h0) in flight
    LOAD_B(0, 0);
    if (more) STAGE_A(0, kt2, 0);
    BAR(); FENCE();
    MFMA_Q(1, 0);
    if (more) asm volatile("s_waitcnt vmcnt(2)" ::: "memory");
    else      asm volatile("s_waitcnt vmcnt(0)" ::: "memory");
    BAR();

    // P5: q00(buf1)
    LOAD_A(1, 0); LOAD_B(1, 0);
    if (more) STAGE_A(0, kt2, 1);
    BAR(); FENCE();
    MFMA_Q(0, 0);
    BAR();
    // P6: q01(buf1)
    LOAD_B(1, 1);
    if (more) STAGE_B(0, kt2, 0);
    BAR(); FENCE();
    MFMA_Q(0, 1);
    BAR();
    // P7: q11(buf1)
    LOAD_A(1, 1);
    if (more) STAGE_B(0, kt2, 1);
    BAR(); FENCE();
    MFMA_Q(1, 1);
    BAR();
    // P8: q10(buf1); gate: t2 fully landed, A(t3,h0) in flight
    LOAD_B(1, 0);
    if (more) STAGE_A(1, kt3, 0);
    BAR(); FENCE();
    MFMA_Q(1, 0);
    if (more) {
      asm volatile("s_waitcnt vmcnt(2)" ::: "memory");
      BAR();
    }
  }
  #undef STAGE_A
  #undef STAGE_B
  #undef LOAD_A
  #undef LOAD_B
  #undef MFMA_Q
  #undef BAR
  #undef FENCE

  // epilogue: acc[mh][m][2s]=gate, acc[mh][m][2s+1]=out; y pre-LN
  #pragma unroll
  for (int s = 0; s < 2; s++) {
    int ocol = colblk*128 + s*64 + wn*16 + ln15;
    float gbv = gate_b[ocol], obv = out_b[ocol];
    #pragma unroll
    for (int mh = 0; mh < 2; mh++) {
      #pragma unroll
      for (int m = 0; m < 4; m++) {
        #pragma unroll
        for (int i = 0; i < 4; i++) {
          size_t r = r0 + mh*128 + wm*64 + m*16 + hi*4 + i;
          float gg = acc[mh][m][s*2+0][i] + gbv;
          float go = acc[mh][m][s*2+1][i] + obv;
          float h  = 0.5f*go*(1.0f + erff(go*0.70710678118654752f));  // exact gelu
          float sg = 1.0f/(1.0f + __expf(-gg));
          float rv = bf2f(A[r*2048 + 1024 + ocol]);
          float xv = x[r*1024 + ocol];
          y[r*1024 + ocol] = h + sg*rv + (1.0f - sg)*xv;
        }
      }
    }
  }
}

// ---------------- K4: LayerNorm in place (wave per row) ---------------------
__global__ __launch_bounds__(256) void k_ln(float* __restrict__ y, const float* __restrict__ g,
                                            const float* __restrict__ b) {
  int row  = blockIdx.x*4 + (threadIdx.x >> 6);
  int lane = threadIdx.x & 63;
  float4* p = (float4*)(y + (size_t)row*1024);
  float4 v[4];
  #pragma unroll
  for (int i = 0; i < 4; i++) v[i] = p[lane + 64*i];
  float s = 0.f;
  #pragma unroll
  for (int i = 0; i < 4; i++) s += v[i].x + v[i].y + v[i].z + v[i].w;
  #pragma unroll
  for (int o = 32; o; o >>= 1) s += __shfl_xor(s, o);
  float mu = s * (1.0f/1024.0f);
  float vs = 0.f;
  #pragma unroll
  for (int i = 0; i < 4; i++) {
    float d0 = v[i].x-mu, d1 = v[i].y-mu, d2 = v[i].z-mu, d3 = v[i].w-mu;
    vs += d0*d0 + d1*d1 + d2*d2 + d3*d3;
  }
  #pragma unroll
  for (int o = 32; o; o >>= 1) vs += __shfl_xor(vs, o);
  float inv = 1.0f / sqrtf(vs*(1.0f/1024.0f) + 1e-5f);
  const float4* gp = (const float4*)g;
  const float4* bp = (const float4*)b;
  #pragma unroll
  for (int i = 0; i < 4; i++) {
    float4 gv = gp[lane+64*i], bv = bp[lane+64*i], o4;
    o4.x = (v[i].x-mu)*inv*gv.x + bv.x;
    o4.y = (v[i].y-mu)*inv*gv.y + bv.y;
    o4.z = (v[i].z-mu)*inv*gv.z + bv.z;
    o4.w = (v[i].w-mu)*inv*gv.w + bv.w;
    p[lane + 64*i] = o4;
  }
}

// ---------------- launch ----------------------------------------------------
extern "C" void kernel_launch(void* const* d_in, const int* in_sizes, int n_in,
                              void* d_out, int out_size, void* d_ws, size_t ws_size,
                              hipStream_t stream) {
  const float* x         = (const float*)d_in[0];
  const float* key_w     = (const float*)d_in[1];
  const float* out_w     = (const float*)d_in[2];
  const float* out_b     = (const float*)d_in[3];
  const float* gate_w    = (const float*)d_in[4];
  const float* gate_b    = (const float*)d_in[5];
  const float* ln_g      = (const float*)d_in[6];
  const float* ln_b      = (const float*)d_in[7];
  const float* pos_table = (const float*)d_in[8];
  const float* mem_keys  = (const float*)d_in[9];
  const float* mem_vals  = (const float*)d_in[10];
  const float* mem_age   = (const float*)d_in[11];
  const float* mem_conf  = (const float*)d_in[12];
  const int*   slot_order= (const int*)d_in[13];

  char* ws = (char*)d_ws;
  u16*   A    = (u16*)(ws + 0);            // combined bf16 [16384][2048]  64 MB
  u16*   Wcat = (u16*)(ws + 67108864);     // interleaved weights [2048][2048] 8 MB
  u16*   Wk   = (u16*)(ws + 75497472);     // key_w  bf16 [32][1024]       64 KB
  u16*   Vals = (u16*)(ws + 75563008);     // mem_vals bf16 [64][1024]    128 KB
  float* kwp  = (float*)(ws + 75694080);   // keys_with_pos [64][33]     8448 B
  float* biasv= (float*)(ws + 75702528);   // salience bias [64]
  float* qk   = (float*)(ws + 75702784);   // qk [16384][32] f32            2 MB
  float* y    = (float*)d_out;

  hipLaunchKernelGGL(k_prep,    dim3(1),    dim3(64),  0, stream,
                     mem_keys, pos_table, slot_order, mem_age, mem_conf, kwp, biasv);
  hipLaunchKernelGGL(k_convert, dim3(8192), dim3(256), 0, stream,
                     x, gate_w, out_w, key_w, mem_vals, A, Wcat, Wk, Vals);
  hipLaunchKernelGGL(k_qk,      dim3(256),  dim3(256), 0, stream, A, Wk, qk);
  hipLaunchKernelGGL(k_retr,    dim3(1024), dim3(256), 0, stream, qk, kwp, biasv, Vals, A);
  hipLaunchKernelGGL(k_gemm,    dim3(512),  dim3(512), 0, stream,
                     A, Wcat, x, out_b, gate_b, y);
  hipLaunchKernelGGL(k_ln,      dim3(4096), dim3(256), 0, stream, y, ln_g, ln_b);
}

// Round 6
// 273.277 us; speedup vs baseline: 1.1933x; 1.0256x over previous
//
#include <hip/hip_runtime.h>
#include <hip/hip_bf16.h>
#include <math.h>

// EpisodicMemory fused pipeline for MI355X (gfx950).
// B=16384, HID=1024, SLOTS=64, KD=32.
// Dominant cost: ONE [16384,2048]x[2048,2048] bf16 MFMA GEMM (gate/out weights
// row-interleaved in 16-col groups) with fused sigmoid/GELU/blend epilogue.
// k_gemm: 8-phase / 2-K-tile iteration, BK=64, 256x256 tile, 8 waves,
// double-buffered LDS (128KB), counted vmcnt(2) at P4/P8 only, chunk-XOR LDS
// swizzle, setprio, and (round 6) rule-#18 pinning: explicit lgkmcnt(0) +
// sched_barrier(0) around each MFMA cluster; kk-outer MFMA ordering;
// dual B register sets (no re-reads; P4/P8 lose their leading barrier).

typedef float    f32x4 __attribute__((ext_vector_type(4)));
typedef short    s16x8 __attribute__((ext_vector_type(8)));
typedef unsigned short u16;
typedef unsigned short u16x8 __attribute__((ext_vector_type(8)));

#define MFMA_BF16(a,b,c) __builtin_amdgcn_mfma_f32_16x16x32_bf16((a),(b),(c),0,0,0)

__device__ __forceinline__ void async16(void* lds, const void* g) {
  __builtin_amdgcn_global_load_lds((const __attribute__((address_space(1))) void*)g,
                                   (__attribute__((address_space(3))) void*)lds, 16, 0, 0);
}

__device__ __forceinline__ u16 f2bf(float f) {
  unsigned u = __float_as_uint(f);
  u += 0x7fffu + ((u >> 16) & 1u);   // RNE
  return (u16)(u >> 16);
}
__device__ __forceinline__ float bf2f(u16 h) {
  return __uint_as_float(((unsigned)h) << 16);
}

// ---------------- K0: per-slot prep (keys_with_pos normalized, bias) --------
__global__ void k_prep(const float* __restrict__ mem_keys, const float* __restrict__ pos_table,
                       const int* __restrict__ slot_order, const float* __restrict__ mem_age,
                       const float* __restrict__ mem_conf,
                       float* __restrict__ kwp /*[64][33] padded*/, float* __restrict__ biasv) {
  int s = threadIdx.x;            // 64 threads = 1 wave
  float age  = mem_age[s];
  float freq = fmaxf(age, 1.0f);
  float fm = freq;
  #pragma unroll
  for (int o = 32; o; o >>= 1) fm = fmaxf(fm, __shfl_xor(fm, o));
  float freq_norm = logf(freq + 1.0f) / (logf(fm + 2.0f) + 1e-8f);
  float recency = expf(-age * (1.0f/200.0f));
  biasv[s] = 0.2f*recency + 0.15f*freq_norm + 0.1f*mem_conf[s] + 0.08f;

  int idx = slot_order[s] & 63;   // % SLOTS (values are arange, nonneg)
  float k[32]; float ss = 0.f;
  #pragma unroll
  for (int d = 0; d < 32; d++) {
    float v = mem_keys[s*32+d] + 0.1f*pos_table[idx*32+d];
    k[d] = v; ss += v*v;
  }
  float inv = 1.0f / fmaxf(sqrtf(ss), 1e-12f);
  #pragma unroll
  for (int d = 0; d < 32; d++) kwp[s*33+d] = k[d]*inv;
}

// ---------------- K1: fp32 -> bf16 conversions ------------------------------
// Weights go to Wcat [2048][2048]: row p = g*32 + h*16 + c holds
// (h==0 ? gate_w : out_w) row (g*16+c).
__global__ __launch_bounds__(256) void k_convert(
    const float* __restrict__ x, const float* __restrict__ gate_w,
    const float* __restrict__ out_w, const float* __restrict__ key_w,
    const float* __restrict__ mem_vals,
    u16* __restrict__ A, u16* __restrict__ Wcat,
    u16* __restrict__ Wk, u16* __restrict__ Vals) {
  const int NX = 4194304, NW = 524288, NK = 8192, NV = 16384;  // float4 groups
  const int total = NX + 2*NW + NK + NV;
  for (int g = blockIdx.x*256 + threadIdx.x; g < total; g += gridDim.x*256) {
    float4 v; u16* dst;
    if (g < NX) {                       // x -> combined[:, 0:1024]
      v = ((const float4*)x)[g];
      int r = g >> 8, c4 = g & 255;
      dst = A + ((size_t)r*2048 + c4*4);
    } else if (g < NX+NW) {             // gate_w -> Wcat interleaved
      int t = g-NX; v = ((const float4*)gate_w)[t];
      int row = t >> 9, grp = t & 511;
      int p = ((row>>4)<<5) + (row&15);
      dst = Wcat + ((size_t)p*2048 + grp*4);
    } else if (g < NX+2*NW) {           // out_w -> Wcat interleaved (+16)
      int t = g-NX-NW; v = ((const float4*)out_w)[t];
      int row = t >> 9, grp = t & 511;
      int p = ((row>>4)<<5) + 16 + (row&15);
      dst = Wcat + ((size_t)p*2048 + grp*4);
    } else if (g < NX+2*NW+NK) {
      int t = g-NX-2*NW; v = ((const float4*)key_w)[t];   dst = Wk + (size_t)t*4;
    } else {
      int t = g-NX-2*NW-NK; v = ((const float4*)mem_vals)[t]; dst = Vals + (size_t)t*4;
    }
    ushort4 o; o.x=f2bf(v.x); o.y=f2bf(v.y); o.z=f2bf(v.z); o.w=f2bf(v.w);
    *(ushort4*)dst = o;
  }
}

// ---------------- K2a: qk = x @ key_w^T  (thin MFMA GEMM) -------------------
__global__ __launch_bounds__(256) void k_qk(const u16* __restrict__ A, const u16* __restrict__ Wk,
                                            float* __restrict__ qk) {
  __shared__ __align__(16) u16 sA[64*64];
  __shared__ __align__(16) u16 sB[32*64];
  int tid = threadIdx.x, lane = tid & 63, w = tid >> 6;
  int r0 = blockIdx.x * 64;
  f32x4 acc[2] = { {0.f,0.f,0.f,0.f}, {0.f,0.f,0.f,0.f} };
  for (int k0 = 0; k0 < 1024; k0 += 64) {
    const char* Ab = (const char*)A + ((size_t)r0*2048 + k0)*2;   // A row stride 4096 B
    #pragma unroll
    for (int i = 0; i < 2; i++) {
      int cidx = tid + i*256;                  // 512 chunks of 16 B
      async16((char*)sA + cidx*16, Ab + (size_t)(cidx>>3)*4096 + (size_t)(cidx&7)*16);
    }
    { const char* Bb = (const char*)Wk + (size_t)k0*2;            // Wk row stride 2048 B
      async16((char*)sB + tid*16, Bb + (size_t)(tid>>3)*2048 + (size_t)(tid&7)*16); }
    __syncthreads();
    #pragma unroll
    for (int kk = 0; kk < 2; kk++) {
      int kb = kk*32 + (lane>>4)*8;
      s16x8 a  = *(const s16x8*)&sA[(w*16 + (lane&15))*64 + kb];
      s16x8 b0 = *(const s16x8*)&sB[(lane&15)*64 + kb];
      s16x8 b1 = *(const s16x8*)&sB[((lane&15)+16)*64 + kb];
      acc[0] = MFMA_BF16(a, b0, acc[0]);
      acc[1] = MFMA_BF16(a, b1, acc[1]);
    }
    __syncthreads();
  }
  int rr = (lane>>4)*4, cc = lane&15;
  #pragma unroll
  for (int n = 0; n < 2; n++)
    #pragma unroll
    for (int i = 0; i < 4; i++)
      qk[(size_t)(r0 + w*16 + rr + i)*32 + n*16 + cc] = acc[n][i];
}

// ---------------- K2b: softmax over slots + retrieved = attn @ mem_vals -----
__global__ __launch_bounds__(256) void k_retr(const float* __restrict__ qk,
                                              const float* __restrict__ kwp,
                                              const float* __restrict__ biasv,
                                              const u16* __restrict__ Vals,
                                              u16* __restrict__ A) {
  __shared__ float sK[64*33];
  __shared__ float sBias[64];
  __shared__ float sQn[16*32];
  __shared__ float sAttn[16*64];
  int tid = threadIdx.x, lane = tid & 63, w = tid >> 6;
  int row0 = blockIdx.x * 16;
  for (int i = tid; i < 64*33; i += 256) sK[i] = kwp[i];
  if (tid < 64) sBias[tid] = biasv[tid];
  __syncthreads();

  int d = lane & 31;
  for (int j = 0; j < 4; j++) {
    int rl = w*4 + j;
    float v = qk[(size_t)(row0+rl)*32 + d];
    float sq = v*v;
    #pragma unroll
    for (int o = 16; o; o >>= 1) sq += __shfl_xor(sq, o);   // 32-lane group sum
    float qn = v / fmaxf(sqrtf(sq), 1e-12f);
    if (lane < 32) sQn[rl*32 + d] = qn;
    float accs = 0.f;
    #pragma unroll
    for (int dd = 0; dd < 32; dd++) accs += sK[lane*33+dd] * sQn[rl*32+dd];
    float sim = accs * 0.17677669529663687f;   // 1/sqrt(32)
    float sal = fminf(fmaxf(0.45f*sim + sBias[lane], 0.0f), 1.0f);
    float mx = sal;
    #pragma unroll
    for (int o = 32; o; o >>= 1) mx = fmaxf(mx, __shfl_xor(mx, o));
    float e = expf(sal - mx);
    float sm = e;
    #pragma unroll
    for (int o = 32; o; o >>= 1) sm += __shfl_xor(sm, o);
    sAttn[rl*64 + lane] = e / sm;
  }
  __syncthreads();

  float acc[4][16];
  #pragma unroll
  for (int j = 0; j < 4; j++)
    #pragma unroll
    for (int i = 0; i < 16; i++) acc[j][i] = 0.f;
  const u16* vp = Vals + lane*16;
  for (int s = 0; s < 64; s++) {
    s16x8 v0 = *(const s16x8*)(vp + (size_t)s*1024);
    s16x8 v1 = *(const s16x8*)(vp + (size_t)s*1024 + 8);
    float vf[16];
    #pragma unroll
    for (int i = 0; i < 8; i++) { vf[i] = bf2f((u16)v0[i]); vf[8+i] = bf2f((u16)v1[i]); }
    #pragma unroll
    for (int j = 0; j < 4; j++) {
      float a = sAttn[(w*4+j)*64 + s];
      #pragma unroll
      for (int i = 0; i < 16; i++) acc[j][i] += a * vf[i];
    }
  }
  #pragma unroll
  for (int j = 0; j < 4; j++) {
    int r = row0 + w*4 + j;
    u16x8 o0, o1;
    #pragma unroll
    for (int i = 0; i < 8; i++) { o0[i] = f2bf(acc[j][i]); o1[i] = f2bf(acc[j][8+i]); }
    u16* dst = A + (size_t)r*2048 + 1024 + lane*16;   // combined[:, 1024:2048]
    *(u16x8*)dst = o0;
    *(u16x8*)(dst + 8) = o1;
  }
}

// ---------------- K3: single interleaved GEMM + fused epilogue --------------
// C = combined[16384,2048] @ Wcat[2048,2048]^T.
// 256x256 tile, 8 waves (2M x 4N), per-wave 128x64 output.
// Iteration = 2 K-tiles (BK=64, buf0/buf1), 8 phases, quadrants q00,q01,q11,
// q10 (reads 12/4/8/0 b128; dual bset register sets, zero re-reads).
// One stage-op (2 global_load_lds) per phase; vmcnt(2) at P4/P8 ends only.
// Rule-#18 pinning: lgkmcnt(0)+sched_barrier(0) before each MFMA cluster,
// sched_barrier(0) after; kk-outer MFMA order (8 indep MFMAs between deps).
__global__ __launch_bounds__(512, 2) void k_gemm(
    const u16* __restrict__ A, const u16* __restrict__ Wcat,
    const float* __restrict__ out_b, const float* __restrict__ gate_b,
    float* __restrict__ y) {
  __shared__ __align__(16) u16 sA[2][16384];   // [buf][half*8192 + row*64 + swz]
  __shared__ __align__(16) u16 sB[2][16384];

  const int tid = threadIdx.x, lane = tid & 63;
  const int w = tid >> 6;
  const int ln15 = lane & 15, hi = lane >> 4;
  const int wm = w >> 2, wn = w & 3;
  const int p7 = ln15 & 7;

  const int colblk = blockIdx.x & 7;   // XCD-resident weight panel
  const int rowblk = blockIdx.x >> 3;
  const size_t r0 = (size_t)rowblk * 256;
  const size_t c0 = (size_t)colblk * 256;

  const u16* gA = A    + r0 * 2048;
  const u16* gB = Wcat + c0 * 2048;

  // staging: half-tile = 128 rows x 64 cols; 1024 chunks of 16B, 2/thread.
  // physical chunk pc of row r holds logical chunk pc ^ (r&7).
  const int i0 = tid, i1 = tid + 512;
  const int sr0 = i0 >> 3, sl0 = (i0 & 7) ^ (sr0 & 7);
  const int sr1 = i1 >> 3, sl1 = (i1 & 7) ^ (sr1 & 7);
  const u16* a0p = gA + (size_t)sr0*2048 + sl0*8;   // + h*262144 + kt*64
  const u16* a1p = gA + (size_t)sr1*2048 + sl1*8;
  const u16* b0p = gB + (size_t)sr0*2048 + sl0*8;
  const u16* b1p = gB + (size_t)sr1*2048 + sl1*8;

  #define STAGE_A(buf, kt, h) do {                                            \
    async16(&sA[buf][(h)*8192 + i0*8], a0p + (size_t)(h)*262144 + (kt)*64);   \
    async16(&sA[buf][(h)*8192 + i1*8], a1p + (size_t)(h)*262144 + (kt)*64);   \
  } while (0)
  #define STAGE_B(buf, kt, h) do {                                            \
    async16(&sB[buf][(h)*8192 + i0*8], b0p + (size_t)(h)*262144 + (kt)*64);   \
    async16(&sB[buf][(h)*8192 + i1*8], b1p + (size_t)(h)*262144 + (kt)*64);   \
  } while (0)

  // ds_read addressing: logical chunk lc -> physical (lc ^ (row&7)); row&7=p7.
  const int c0k = (hi ^ p7) * 8;          // kk=0: lc = hi
  const int c1k = ((4 | hi) ^ p7) * 8;    // kk=1: lc = 4|hi
  const int arow = (wm*64 + ln15) * 64;   // + m*1024 + mh*8192
  const int brow = (wn*32 + ln15) * 64;   // + n2*1024 + nh*8192

  s16x8 aset[4][2], bset0[2][2], bset1[2][2];
  #define LOAD_A(buf, mh) do {                                                \
    _Pragma("unroll")                                                         \
    for (int m = 0; m < 4; m++) {                                             \
      aset[m][0] = *(const s16x8*)&sA[buf][(mh)*8192 + arow + m*1024 + c0k];  \
      aset[m][1] = *(const s16x8*)&sA[buf][(mh)*8192 + arow + m*1024 + c1k];  \
    }                                                                         \
  } while (0)
  #define LOAD_B0(buf) do {                                                   \
    _Pragma("unroll")                                                         \
    for (int n2 = 0; n2 < 2; n2++) {                                          \
      bset0[n2][0] = *(const s16x8*)&sB[buf][brow + n2*1024 + c0k];           \
      bset0[n2][1] = *(const s16x8*)&sB[buf][brow + n2*1024 + c1k];           \
    }                                                                         \
  } while (0)
  #define LOAD_B1(buf) do {                                                   \
    _Pragma("unroll")                                                         \
    for (int n2 = 0; n2 < 2; n2++) {                                          \
      bset1[n2][0] = *(const s16x8*)&sB[buf][8192 + brow + n2*1024 + c0k];    \
      bset1[n2][1] = *(const s16x8*)&sB[buf][8192 + brow + n2*1024 + c1k];    \
    }                                                                         \
  } while (0)

  f32x4 acc[2][4][4];
  #pragma unroll
  for (int mh = 0; mh < 2; mh++)
    #pragma unroll
    for (int m = 0; m < 4; m++)
      #pragma unroll
      for (int n = 0; n < 4; n++) acc[mh][m][n] = {0.f, 0.f, 0.f, 0.f};

  // kk-outer: 8 independent MFMAs between dependent accumulator reuses
  #define MFMA_Q(mh, nh, BS) do {                                             \
    __builtin_amdgcn_s_setprio(1);                                            \
    _Pragma("unroll")                                                         \
    for (int kk = 0; kk < 2; kk++)                                            \
      _Pragma("unroll")                                                       \
      for (int m = 0; m < 4; m++)                                             \
        _Pragma("unroll")                                                     \
        for (int n2 = 0; n2 < 2; n2++)                                        \
          acc[mh][m][(nh)*2+n2] = MFMA_BF16(aset[m][kk], BS[n2][kk], acc[mh][m][(nh)*2+n2]); \
    __builtin_amdgcn_s_setprio(0);                                            \
  } while (0)

  #define BAR()    __builtin_amdgcn_s_barrier()
  #define LGKM0()  asm volatile("s_waitcnt lgkmcnt(0)" ::: "memory")
  #define SCHED0() __builtin_amdgcn_sched_barrier(0)

  // prologue: t0 -> buf0 (4 ops), t1 A-h0 -> buf1 (1 op); gate t0 complete
  STAGE_A(0, 0, 0);
  STAGE_A(0, 0, 1);
  STAGE_B(0, 0, 0);
  STAGE_B(0, 0, 1);
  STAGE_A(1, 1, 0);
  asm volatile("s_waitcnt vmcnt(2)" ::: "memory");
  BAR();

  #pragma unroll 1
  for (int i = 0; i < 16; ++i) {
    const bool more = (i < 15);
    const int kt1 = 2*i + 1, kt2 = 2*i + 2, kt3 = 2*i + 3;

    // P1: q00(buf0): 12 ds_reads; stage A(t1,h1)
    LOAD_A(0, 0); LOAD_B0(0);
    STAGE_A(1, kt1, 1);
    BAR(); LGKM0(); SCHED0();
    MFMA_Q(0, 0, bset0);
    SCHED0();
    BAR();
    // P2: q01(buf0): 4 ds_reads; stage B(t1,h0)
    LOAD_B1(0);
    STAGE_B(1, kt1, 0);
    BAR(); LGKM0(); SCHED0();
    MFMA_Q(0, 1, bset1);
    SCHED0();
    BAR();
    // P3: q11(buf0): 8 ds_reads; stage B(t1,h1)
    LOAD_A(0, 1);
    STAGE_B(1, kt1, 1);
    BAR(); LGKM0(); SCHED0();
    MFMA_Q(1, 1, bset1);
    SCHED0();
    BAR();
    // P4: q10(buf0): 0 ds_reads (regs); stage A(t2,h0) into freed buf0; gate
    if (more) STAGE_A(0, kt2, 0);
    SCHED0();
    MFMA_Q(1, 0, bset0);
    SCHED0();
    if (more) asm volatile("s_waitcnt vmcnt(2)" ::: "memory");  // t1 landed
    else      asm volatile("s_waitcnt vmcnt(0)" ::: "memory");
    BAR();

    // P5: q00(buf1): 12 ds_reads; stage A(t2,h1)
    LOAD_A(1, 0); LOAD_B0(1);
    if (more) STAGE_A(0, kt2, 1);
    BAR(); LGKM0(); SCHED0();
    MFMA_Q(0, 0, bset0);
    SCHED0();
    BAR();
    // P6: q01(buf1): 4 ds_reads; stage B(t2,h0)
    LOAD_B1(1);
    if (more) STAGE_B(0, kt2, 0);
    BAR(); LGKM0(); SCHED0();
    MFMA_Q(0, 1, bset1);
    SCHED0();
    BAR();
    // P7: q11(buf1): 8 ds_reads; stage B(t2,h1)
    LOAD_A(1, 1);
    if (more) STAGE_B(0, kt2, 1);
    BAR(); LGKM0(); SCHED0();
    MFMA_Q(1, 1, bset1);
    SCHED0();
    BAR();
    // P8: q10(buf1): 0 ds_reads; stage A(t3,h0) into freed buf1; gate
    if (more) STAGE_A(1, kt3, 0);
    SCHED0();
    MFMA_Q(1, 0, bset0);
    SCHED0();
    if (more) {
      asm volatile("s_waitcnt vmcnt(2)" ::: "memory");          // t2 landed
      BAR();
    }
  }
  #undef STAGE_A
  #undef STAGE_B
  #undef LOAD_A
  #undef LOAD_B0
  #undef LOAD_B1
  #undef MFMA_Q
  #undef BAR
  #undef LGKM0
  #undef SCHED0

  // epilogue: acc[mh][m][2s]=gate, acc[mh][m][2s+1]=out; y pre-LN.
  // x is read back from A's bf16 left half (same rows as rv; saves 64MB f32).
  #pragma unroll
  for (int s = 0; s < 2; s++) {
    int ocol = colblk*128 + s*64 + wn*16 + ln15;
    float gbv = gate_b[ocol], obv = out_b[ocol];
    #pragma unroll
    for (int mh = 0; mh < 2; mh++) {
      #pragma unroll
      for (int m = 0; m < 4; m++) {
        #pragma unroll
        for (int i = 0; i < 4; i++) {
          size_t r = r0 + mh*128 + wm*64 + m*16 + hi*4 + i;
          float gg = acc[mh][m][s*2+0][i] + gbv;
          float go = acc[mh][m][s*2+1][i] + obv;
          float h  = 0.5f*go*(1.0f + erff(go*0.70710678118654752f));  // exact gelu
          float sg = 1.0f/(1.0f + __expf(-gg));
          float rv = bf2f(A[r*2048 + 1024 + ocol]);
          float xv = bf2f(A[r*2048 + ocol]);
          y[r*1024 + ocol] = h + sg*rv + (1.0f - sg)*xv;
        }
      }
    }
  }
}

// ---------------- K4: LayerNorm in place (wave per row) ---------------------
__global__ __launch_bounds__(256) void k_ln(float* __restrict__ y, const float* __restrict__ g,
                                            const float* __restrict__ b) {
  int row  = blockIdx.x*4 + (threadIdx.x >> 6);
  int lane = threadIdx.x & 63;
  float4* p = (float4*)(y + (size_t)row*1024);
  float4 v[4];
  #pragma unroll
  for (int i = 0; i < 4; i++) v[i] = p[lane + 64*i];
  float s = 0.f;
  #pragma unroll
  for (int i = 0; i < 4; i++) s += v[i].x + v[i].y + v[i].z + v[i].w;
  #pragma unroll
  for (int o = 32; o; o >>= 1) s += __shfl_xor(s, o);
  float mu = s * (1.0f/1024.0f);
  float vs = 0.f;
  #pragma unroll
  for (int i = 0; i < 4; i++) {
    float d0 = v[i].x-mu, d1 = v[i].y-mu, d2 = v[i].z-mu, d3 = v[i].w-mu;
    vs += d0*d0 + d1*d1 + d2*d2 + d3*d3;
  }
  #pragma unroll
  for (int o = 32; o; o >>= 1) vs += __shfl_xor(vs, o);
  float inv = 1.0f / sqrtf(vs*(1.0f/1024.0f) + 1e-5f);
  const float4* gp = (const float4*)g;
  const float4* bp = (const float4*)b;
  #pragma unroll
  for (int i = 0; i < 4; i++) {
    float4 gv = gp[lane+64*i], bv = bp[lane+64*i], o4;
    o4.x = (v[i].x-mu)*inv*gv.x + bv.x;
    o4.y = (v[i].y-mu)*inv*gv.y + bv.y;
    o4.z = (v[i].z-mu)*inv*gv.z + bv.z;
    o4.w = (v[i].w-mu)*inv*gv.w + bv.w;
    p[lane + 64*i] = o4;
  }
}

// ---------------- launch ----------------------------------------------------
extern "C" void kernel_launch(void* const* d_in, const int* in_sizes, int n_in,
                              void* d_out, int out_size, void* d_ws, size_t ws_size,
                              hipStream_t stream) {
  const float* x         = (const float*)d_in[0];
  const float* key_w     = (const float*)d_in[1];
  const float* out_w     = (const float*)d_in[2];
  const float* out_b     = (const float*)d_in[3];
  const float* gate_w    = (const float*)d_in[4];
  const float* gate_b    = (const float*)d_in[5];
  const float* ln_g      = (const float*)d_in[6];
  const float* ln_b      = (const float*)d_in[7];
  const float* pos_table = (const float*)d_in[8];
  const float* mem_keys  = (const float*)d_in[9];
  const float* mem_vals  = (const float*)d_in[10];
  const float* mem_age   = (const float*)d_in[11];
  const float* mem_conf  = (const float*)d_in[12];
  const int*   slot_order= (const int*)d_in[13];

  char* ws = (char*)d_ws;
  u16*   A    = (u16*)(ws + 0);            // combined bf16 [16384][2048]  64 MB
  u16*   Wcat = (u16*)(ws + 67108864);     // interleaved weights [2048][2048] 8 MB
  u16*   Wk   = (u16*)(ws + 75497472);     // key_w  bf16 [32][1024]       64 KB
  u16*   Vals = (u16*)(ws + 75563008);     // mem_vals bf16 [64][1024]    128 KB
  float* kwp  = (float*)(ws + 75694080);   // keys_with_pos [64][33]     8448 B
  float* biasv= (float*)(ws + 75702528);   // salience bias [64]
  float* qk   = (float*)(ws + 75702784);   // qk [16384][32] f32            2 MB
  float* y    = (float*)d_out;

  hipLaunchKernelGGL(k_prep,    dim3(1),    dim3(64),  0, stream,
                     mem_keys, pos_table, slot_order, mem_age, mem_conf, kwp, biasv);
  hipLaunchKernelGGL(k_convert, dim3(8192), dim3(256), 0, stream,
                     x, gate_w, out_w, key_w, mem_vals, A, Wcat, Wk, Vals);
  hipLaunchKernelGGL(k_qk,      dim3(256),  dim3(256), 0, stream, A, Wk, qk);
  hipLaunchKernelGGL(k_retr,    dim3(1024), dim3(256), 0, stream, qk, kwp, biasv, Vals, A);
  hipLaunchKernelGGL(k_gemm,    dim3(512),  dim3(512), 0, stream,
                     A, Wcat, out_b, gate_b, y);
  hipLaunchKernelGGL(k_ln,      dim3(4096), dim3(256), 0, stream, y, ln_g, ln_b);
}

// Round 7
// 272.381 us; speedup vs baseline: 1.1972x; 1.0033x over previous
//
#include <hip/hip_runtime.h>
#include <hip/hip_bf16.h>
#include <math.h>

// EpisodicMemory fused pipeline for MI355X (gfx950).
// B=16384, HID=1024, SLOTS=64, KD=32.
// Dominant cost: ONE [16384,2048]x[2048,2048] bf16 MFMA GEMM (gate/out weights
// row-interleaved in 16-col groups) with fused sigmoid/GELU/blend epilogue.
// k_gemm round 7: pipelined-read 8-phase. Fragments are ds_read ONE PHASE
// EARLY into double register sets; each phase = [reads for next phase]
// [1 stage-op][16 MFMA on last phase's registers][lgkmcnt(0); s_barrier].
// One barrier per phase; vmcnt(4) gates at P4/P8 only; no sched_barrier.
//
// Ledger (iter i, tiles t0=2i->buf0, t1=2i+1->buf1, t2=2i+2, t3=2i+3):
//  reads:  P1:bB<-B(t0,h1) P2:aB<-A(t0,h1) P3:aA<-A(t1,h0) P4:bB<-B(t1,h1)
//          P5:bA<-B(t1,h0) P6:aB<-A(t1,h1) P7:aA<-A(t2,h0) P8:bA<-B(t2,h0)
//  MFMA:   P1:q00(aA,bA) P2:q01(aA,bB) P3:q11(aB,bB) P4:q10(aB,bA)   [t0]
//          P5:q01(aA,bB) P6:q00(aA,bA) P7:q10(aB,bA) P8:q11(aB,bB)   [t1]
//  stages: P1:B(t2,h0) P2:B(t2,h1) P3:A(t2,h1) P4:A(t3,h0)
//          P5:B(t3,h1) P6:B(t3,h0) P7:A(t3,h1) P8:A(t4,h0)
//  each stage's region was last read exactly 1 phase earlier (drained by the
//  phase-end lgkmcnt(0)+barrier); each read's stage is confirmed by a gate
//  >=3 phases after issue (end-P4 / end-P8, vmcnt(4) = 2 ops outstanding).

typedef float    f32x4 __attribute__((ext_vector_type(4)));
typedef short    s16x8 __attribute__((ext_vector_type(8)));
typedef unsigned short u16;
typedef unsigned short u16x8 __attribute__((ext_vector_type(8)));

#define MFMA_BF16(a,b,c) __builtin_amdgcn_mfma_f32_16x16x32_bf16((a),(b),(c),0,0,0)

__device__ __forceinline__ void async16(void* lds, const void* g) {
  __builtin_amdgcn_global_load_lds((const __attribute__((address_space(1))) void*)g,
                                   (__attribute__((address_space(3))) void*)lds, 16, 0, 0);
}

__device__ __forceinline__ u16 f2bf(float f) {
  unsigned u = __float_as_uint(f);
  u += 0x7fffu + ((u >> 16) & 1u);   // RNE
  return (u16)(u >> 16);
}
__device__ __forceinline__ float bf2f(u16 h) {
  return __uint_as_float(((unsigned)h) << 16);
}

// ---------------- K0: per-slot prep (keys_with_pos normalized, bias) --------
__global__ void k_prep(const float* __restrict__ mem_keys, const float* __restrict__ pos_table,
                       const int* __restrict__ slot_order, const float* __restrict__ mem_age,
                       const float* __restrict__ mem_conf,
                       float* __restrict__ kwp /*[64][33] padded*/, float* __restrict__ biasv) {
  int s = threadIdx.x;            // 64 threads = 1 wave
  float age  = mem_age[s];
  float freq = fmaxf(age, 1.0f);
  float fm = freq;
  #pragma unroll
  for (int o = 32; o; o >>= 1) fm = fmaxf(fm, __shfl_xor(fm, o));
  float freq_norm = logf(freq + 1.0f) / (logf(fm + 2.0f) + 1e-8f);
  float recency = expf(-age * (1.0f/200.0f));
  biasv[s] = 0.2f*recency + 0.15f*freq_norm + 0.1f*mem_conf[s] + 0.08f;

  int idx = slot_order[s] & 63;   // % SLOTS (values are arange, nonneg)
  float k[32]; float ss = 0.f;
  #pragma unroll
  for (int d = 0; d < 32; d++) {
    float v = mem_keys[s*32+d] + 0.1f*pos_table[idx*32+d];
    k[d] = v; ss += v*v;
  }
  float inv = 1.0f / fmaxf(sqrtf(ss), 1e-12f);
  #pragma unroll
  for (int d = 0; d < 32; d++) kwp[s*33+d] = k[d]*inv;
}

// ---------------- K1: fp32 -> bf16 conversions ------------------------------
// Weights go to Wcat [2048][2048]: row p = g*32 + h*16 + c holds
// (h==0 ? gate_w : out_w) row (g*16+c).
__global__ __launch_bounds__(256) void k_convert(
    const float* __restrict__ x, const float* __restrict__ gate_w,
    const float* __restrict__ out_w, const float* __restrict__ key_w,
    const float* __restrict__ mem_vals,
    u16* __restrict__ A, u16* __restrict__ Wcat,
    u16* __restrict__ Wk, u16* __restrict__ Vals) {
  const int NX = 4194304, NW = 524288, NK = 8192, NV = 16384;  // float4 groups
  const int total = NX + 2*NW + NK + NV;
  for (int g = blockIdx.x*256 + threadIdx.x; g < total; g += gridDim.x*256) {
    float4 v; u16* dst;
    if (g < NX) {                       // x -> combined[:, 0:1024]
      v = ((const float4*)x)[g];
      int r = g >> 8, c4 = g & 255;
      dst = A + ((size_t)r*2048 + c4*4);
    } else if (g < NX+NW) {             // gate_w -> Wcat interleaved
      int t = g-NX; v = ((const float4*)gate_w)[t];
      int row = t >> 9, grp = t & 511;
      int p = ((row>>4)<<5) + (row&15);
      dst = Wcat + ((size_t)p*2048 + grp*4);
    } else if (g < NX+2*NW) {           // out_w -> Wcat interleaved (+16)
      int t = g-NX-NW; v = ((const float4*)out_w)[t];
      int row = t >> 9, grp = t & 511;
      int p = ((row>>4)<<5) + 16 + (row&15);
      dst = Wcat + ((size_t)p*2048 + grp*4);
    } else if (g < NX+2*NW+NK) {
      int t = g-NX-2*NW; v = ((const float4*)key_w)[t];   dst = Wk + (size_t)t*4;
    } else {
      int t = g-NX-2*NW-NK; v = ((const float4*)mem_vals)[t]; dst = Vals + (size_t)t*4;
    }
    ushort4 o; o.x=f2bf(v.x); o.y=f2bf(v.y); o.z=f2bf(v.z); o.w=f2bf(v.w);
    *(ushort4*)dst = o;
  }
}

// ---------------- K2a: qk = x @ key_w^T  (thin MFMA GEMM) -------------------
__global__ __launch_bounds__(256) void k_qk(const u16* __restrict__ A, const u16* __restrict__ Wk,
                                            float* __restrict__ qk) {
  __shared__ __align__(16) u16 sA[64*64];
  __shared__ __align__(16) u16 sB[32*64];
  int tid = threadIdx.x, lane = tid & 63, w = tid >> 6;
  int r0 = blockIdx.x * 64;
  f32x4 acc[2] = { {0.f,0.f,0.f,0.f}, {0.f,0.f,0.f,0.f} };
  for (int k0 = 0; k0 < 1024; k0 += 64) {
    const char* Ab = (const char*)A + ((size_t)r0*2048 + k0)*2;   // A row stride 4096 B
    #pragma unroll
    for (int i = 0; i < 2; i++) {
      int cidx = tid + i*256;                  // 512 chunks of 16 B
      async16((char*)sA + cidx*16, Ab + (size_t)(cidx>>3)*4096 + (size_t)(cidx&7)*16);
    }
    { const char* Bb = (const char*)Wk + (size_t)k0*2;            // Wk row stride 2048 B
      async16((char*)sB + tid*16, Bb + (size_t)(tid>>3)*2048 + (size_t)(tid&7)*16); }
    __syncthreads();
    #pragma unroll
    for (int kk = 0; kk < 2; kk++) {
      int kb = kk*32 + (lane>>4)*8;
      s16x8 a  = *(const s16x8*)&sA[(w*16 + (lane&15))*64 + kb];
      s16x8 b0 = *(const s16x8*)&sB[(lane&15)*64 + kb];
      s16x8 b1 = *(const s16x8*)&sB[((lane&15)+16)*64 + kb];
      acc[0] = MFMA_BF16(a, b0, acc[0]);
      acc[1] = MFMA_BF16(a, b1, acc[1]);
    }
    __syncthreads();
  }
  int rr = (lane>>4)*4, cc = lane&15;
  #pragma unroll
  for (int n = 0; n < 2; n++)
    #pragma unroll
    for (int i = 0; i < 4; i++)
      qk[(size_t)(r0 + w*16 + rr + i)*32 + n*16 + cc] = acc[n][i];
}

// ---------------- K2b: softmax over slots + retrieved = attn @ mem_vals -----
__global__ __launch_bounds__(256) void k_retr(const float* __restrict__ qk,
                                              const float* __restrict__ kwp,
                                              const float* __restrict__ biasv,
                                              const u16* __restrict__ Vals,
                                              u16* __restrict__ A) {
  __shared__ float sK[64*33];
  __shared__ float sBias[64];
  __shared__ float sQn[16*32];
  __shared__ float sAttn[16*64];
  int tid = threadIdx.x, lane = tid & 63, w = tid >> 6;
  int row0 = blockIdx.x * 16;
  for (int i = tid; i < 64*33; i += 256) sK[i] = kwp[i];
  if (tid < 64) sBias[tid] = biasv[tid];
  __syncthreads();

  int d = lane & 31;
  for (int j = 0; j < 4; j++) {
    int rl = w*4 + j;
    float v = qk[(size_t)(row0+rl)*32 + d];
    float sq = v*v;
    #pragma unroll
    for (int o = 16; o; o >>= 1) sq += __shfl_xor(sq, o);   // 32-lane group sum
    float qn = v / fmaxf(sqrtf(sq), 1e-12f);
    if (lane < 32) sQn[rl*32 + d] = qn;
    float accs = 0.f;
    #pragma unroll
    for (int dd = 0; dd < 32; dd++) accs += sK[lane*33+dd] * sQn[rl*32+dd];
    float sim = accs * 0.17677669529663687f;   // 1/sqrt(32)
    float sal = fminf(fmaxf(0.45f*sim + sBias[lane], 0.0f), 1.0f);
    float mx = sal;
    #pragma unroll
    for (int o = 32; o; o >>= 1) mx = fmaxf(mx, __shfl_xor(mx, o));
    float e = expf(sal - mx);
    float sm = e;
    #pragma unroll
    for (int o = 32; o; o >>= 1) sm += __shfl_xor(sm, o);
    sAttn[rl*64 + lane] = e / sm;
  }
  __syncthreads();

  float acc[4][16];
  #pragma unroll
  for (int j = 0; j < 4; j++)
    #pragma unroll
    for (int i = 0; i < 16; i++) acc[j][i] = 0.f;
  const u16* vp = Vals + lane*16;
  for (int s = 0; s < 64; s++) {
    s16x8 v0 = *(const s16x8*)(vp + (size_t)s*1024);
    s16x8 v1 = *(const s16x8*)(vp + (size_t)s*1024 + 8);
    float vf[16];
    #pragma unroll
    for (int i = 0; i < 8; i++) { vf[i] = bf2f((u16)v0[i]); vf[8+i] = bf2f((u16)v1[i]); }
    #pragma unroll
    for (int j = 0; j < 4; j++) {
      float a = sAttn[(w*4+j)*64 + s];
      #pragma unroll
      for (int i = 0; i < 16; i++) acc[j][i] += a * vf[i];
    }
  }
  #pragma unroll
  for (int j = 0; j < 4; j++) {
    int r = row0 + w*4 + j;
    u16x8 o0, o1;
    #pragma unroll
    for (int i = 0; i < 8; i++) { o0[i] = f2bf(acc[j][i]); o1[i] = f2bf(acc[j][8+i]); }
    u16* dst = A + (size_t)r*2048 + 1024 + lane*16;   // combined[:, 1024:2048]
    *(u16x8*)dst = o0;
    *(u16x8*)(dst + 8) = o1;
  }
}

// ---------------- K3: single interleaved GEMM + fused epilogue --------------
__global__ __launch_bounds__(512, 2) void k_gemm(
    const u16* __restrict__ A, const u16* __restrict__ Wcat,
    const float* __restrict__ out_b, const float* __restrict__ gate_b,
    float* __restrict__ y) {
  __shared__ __align__(16) u16 sA[2][16384];   // [buf][half*8192 + row*64 + swz]
  __shared__ __align__(16) u16 sB[2][16384];

  const int tid = threadIdx.x, lane = tid & 63;
  const int w = tid >> 6;
  const int ln15 = lane & 15, hi = lane >> 4;
  const int wm = w >> 2, wn = w & 3;
  const int p7 = ln15 & 7;

  const int colblk = blockIdx.x & 7;   // XCD-resident weight panel
  const int rowblk = blockIdx.x >> 3;
  const size_t r0 = (size_t)rowblk * 256;
  const size_t c0 = (size_t)colblk * 256;

  const u16* gA = A    + r0 * 2048;
  const u16* gB = Wcat + c0 * 2048;

  // staging: half-tile = 128 rows x 64 cols; 1024 chunks of 16B, 2/thread.
  // physical chunk pc of row r holds logical chunk pc ^ (r&7).
  const int i0 = tid, i1 = tid + 512;
  const int sr0 = i0 >> 3, sl0 = (i0 & 7) ^ (sr0 & 7);
  const int sr1 = i1 >> 3, sl1 = (i1 & 7) ^ (sr1 & 7);
  const u16* a0p = gA + (size_t)sr0*2048 + sl0*8;   // + h*262144 + kt*64
  const u16* a1p = gA + (size_t)sr1*2048 + sl1*8;
  const u16* b0p = gB + (size_t)sr0*2048 + sl0*8;
  const u16* b1p = gB + (size_t)sr1*2048 + sl1*8;

  #define STAGE_A(buf, kt, h) do {                                            \
    async16(&sA[buf][(h)*8192 + i0*8], a0p + (size_t)(h)*262144 + (kt)*64);   \
    async16(&sA[buf][(h)*8192 + i1*8], a1p + (size_t)(h)*262144 + (kt)*64);   \
  } while (0)
  #define STAGE_B(buf, kt, h) do {                                            \
    async16(&sB[buf][(h)*8192 + i0*8], b0p + (size_t)(h)*262144 + (kt)*64);   \
    async16(&sB[buf][(h)*8192 + i1*8], b1p + (size_t)(h)*262144 + (kt)*64);   \
  } while (0)

  // ds_read addressing: logical chunk lc -> physical (lc ^ (row&7)); row&7=p7.
  const int c0k = (hi ^ p7) * 8;          // kk=0: lc = hi
  const int c1k = ((4 | hi) ^ p7) * 8;    // kk=1: lc = 4|hi
  const int arow = (wm*64 + ln15) * 64;   // + m*1024 + mh*8192
  const int brow = (wn*32 + ln15) * 64;   // + n2*1024 + nh*8192

  s16x8 aA[4][2], aB[4][2], bA[2][2], bB[2][2];
  #define LOAD_A(DST, buf, mh) do {                                           \
    _Pragma("unroll")                                                         \
    for (int m = 0; m < 4; m++) {                                             \
      DST[m][0] = *(const s16x8*)&sA[buf][(mh)*8192 + arow + m*1024 + c0k];   \
      DST[m][1] = *(const s16x8*)&sA[buf][(mh)*8192 + arow + m*1024 + c1k];   \
    }                                                                         \
  } while (0)
  #define LOAD_B(DST, buf, nh) do {                                           \
    _Pragma("unroll")                                                         \
    for (int n2 = 0; n2 < 2; n2++) {                                          \
      DST[n2][0] = *(const s16x8*)&sB[buf][(nh)*8192 + brow + n2*1024 + c0k]; \
      DST[n2][1] = *(const s16x8*)&sB[buf][(nh)*8192 + brow + n2*1024 + c1k]; \
    }                                                                         \
  } while (0)

  f32x4 acc[2][4][4];
  #pragma unroll
  for (int mh = 0; mh < 2; mh++)
    #pragma unroll
    for (int m = 0; m < 4; m++)
      #pragma unroll
      for (int n = 0; n < 4; n++) acc[mh][m][n] = {0.f, 0.f, 0.f, 0.f};

  // kk-outer: 8 independent MFMAs between dependent accumulator reuses
  #define MFMA_Q(mh, nh, AS, BS) do {                                         \
    __builtin_amdgcn_s_setprio(1);                                            \
    _Pragma("unroll")                                                         \
    for (int kk = 0; kk < 2; kk++)                                            \
      _Pragma("unroll")                                                       \
      for (int m = 0; m < 4; m++)                                             \
        _Pragma("unroll")                                                     \
        for (int n2 = 0; n2 < 2; n2++)                                        \
          acc[mh][m][(nh)*2+n2] = MFMA_BF16(AS[m][kk], BS[n2][kk], acc[mh][m][(nh)*2+n2]); \
    __builtin_amdgcn_s_setprio(0);                                            \
  } while (0)

  #define PHASE_END() do {                                                    \
    asm volatile("s_waitcnt lgkmcnt(0)" ::: "memory");                        \
    __builtin_amdgcn_s_barrier();                                             \
    asm volatile("" ::: "memory");                                            \
  } while (0)
  #define GATE_END(N) do {                                                    \
    asm volatile("s_waitcnt vmcnt(" #N ") lgkmcnt(0)" ::: "memory");          \
    __builtin_amdgcn_s_barrier();                                             \
    asm volatile("" ::: "memory");                                            \
  } while (0)

  // prologue: ops1-8 = t0{Ah0,Bh0,Bh1,Ah1}, t1{Ah0,Bh1,Bh0,Ah1};
  // vmcnt(2) confirms ops1-7; read aA,bA; drain; op9 = A(2,h0).
  STAGE_A(0, 0, 0);
  STAGE_B(0, 0, 0);
  STAGE_B(0, 0, 1);
  STAGE_A(0, 0, 1);
  STAGE_A(1, 1, 0);
  STAGE_B(1, 1, 1);
  STAGE_B(1, 1, 0);
  STAGE_A(1, 1, 1);
  GATE_END(2);
  LOAD_A(aA, 0, 0);
  LOAD_B(bA, 0, 0);
  PHASE_END();          // drain prologue reads before op9 can overwrite
  STAGE_A(0, 2, 0);     // op9

  #pragma unroll 1
  for (int i = 0; i < 16; ++i) {
    const int t2 = 2*i + 2, t3 = 2*i + 3, t4 = 2*i + 4;
    // kt >= 32 stages read safely-wrapping garbage inside ws; never consumed.

    // P1 [t0 q00: aA x bA]; reads bB<-B(t0,h1); stage B(t2,h0)
    LOAD_B(bB, 0, 1);
    STAGE_B(0, t2, 0);
    MFMA_Q(0, 0, aA, bA);
    PHASE_END();
    // P2 [t0 q01: aA x bB]; reads aB<-A(t0,h1); stage B(t2,h1)
    LOAD_A(aB, 0, 1);
    STAGE_B(0, t2, 1);
    MFMA_Q(0, 1, aA, bB);
    PHASE_END();
    // P3 [t0 q11: aB x bB]; reads aA<-A(t1,h0); stage A(t2,h1)
    LOAD_A(aA, 1, 0);
    STAGE_A(0, t2, 1);
    MFMA_Q(1, 1, aB, bB);
    PHASE_END();
    // P4 [t0 q10: aB x bA]; reads bB<-B(t1,h1); stage A(t3,h0); GATE
    LOAD_B(bB, 1, 1);
    STAGE_A(1, t3, 0);
    MFMA_Q(1, 0, aB, bA);
    GATE_END(4);
    // P5 [t1 q01: aA x bB]; reads bA<-B(t1,h0); stage B(t3,h1)
    LOAD_B(bA, 1, 0);
    STAGE_B(1, t3, 1);
    MFMA_Q(0, 1, aA, bB);
    PHASE_END();
    // P6 [t1 q00: aA x bA]; reads aB<-A(t1,h1); stage B(t3,h0)
    LOAD_A(aB, 1, 1);
    STAGE_B(1, t3, 0);
    MFMA_Q(0, 0, aA, bA);
    PHASE_END();
    // P7 [t1 q10: aB x bA]; reads aA<-A(t2,h0); stage A(t3,h1)
    LOAD_A(aA, 0, 0);
    STAGE_A(1, t3, 1);
    MFMA_Q(1, 0, aB, bA);
    PHASE_END();
    // P8 [t1 q11: aB x bB]; reads bA<-B(t2,h0); stage A(t4,h0); GATE
    LOAD_B(bA, 0, 0);
    STAGE_A(0, t4, 0);
    MFMA_Q(1, 1, aB, bB);
    GATE_END(4);
  }
  #undef STAGE_A
  #undef STAGE_B
  #undef LOAD_A
  #undef LOAD_B
  #undef MFMA_Q
  #undef PHASE_END
  #undef GATE_END

  // epilogue: acc[mh][m][2s]=gate, acc[mh][m][2s+1]=out; y pre-LN.
  // x read back from A's bf16 left half (saves the 64MB f32 re-read).
  #pragma unroll
  for (int s = 0; s < 2; s++) {
    int ocol = colblk*128 + s*64 + wn*16 + ln15;
    float gbv = gate_b[ocol], obv = out_b[ocol];
    #pragma unroll
    for (int mh = 0; mh < 2; mh++) {
      #pragma unroll
      for (int m = 0; m < 4; m++) {
        #pragma unroll
        for (int i = 0; i < 4; i++) {
          size_t r = r0 + mh*128 + wm*64 + m*16 + hi*4 + i;
          float gg = acc[mh][m][s*2+0][i] + gbv;
          float go = acc[mh][m][s*2+1][i] + obv;
          float h  = 0.5f*go*(1.0f + erff(go*0.70710678118654752f));  // exact gelu
          float sg = 1.0f/(1.0f + __expf(-gg));
          float rv = bf2f(A[r*2048 + 1024 + ocol]);
          float xv = bf2f(A[r*2048 + ocol]);
          y[r*1024 + ocol] = h + sg*rv + (1.0f - sg)*xv;
        }
      }
    }
  }
}

// ---------------- K4: LayerNorm in place (wave per row) ---------------------
__global__ __launch_bounds__(256) void k_ln(float* __restrict__ y, const float* __restrict__ g,
                                            const float* __restrict__ b) {
  int row  = blockIdx.x*4 + (threadIdx.x >> 6);
  int lane = threadIdx.x & 63;
  float4* p = (float4*)(y + (size_t)row*1024);
  float4 v[4];
  #pragma unroll
  for (int i = 0; i < 4; i++) v[i] = p[lane + 64*i];
  float s = 0.f;
  #pragma unroll
  for (int i = 0; i < 4; i++) s += v[i].x + v[i].y + v[i].z + v[i].w;
  #pragma unroll
  for (int o = 32; o; o >>= 1) s += __shfl_xor(s, o);
  float mu = s * (1.0f/1024.0f);
  float vs = 0.f;
  #pragma unroll
  for (int i = 0; i < 4; i++) {
    float d0 = v[i].x-mu, d1 = v[i].y-mu, d2 = v[i].z-mu, d3 = v[i].w-mu;
    vs += d0*d0 + d1*d1 + d2*d2 + d3*d3;
  }
  #pragma unroll
  for (int o = 32; o; o >>= 1) vs += __shfl_xor(vs, o);
  float inv = 1.0f / sqrtf(vs*(1.0f/1024.0f) + 1e-5f);
  const float4* gp = (const float4*)g;
  const float4* bp = (const float4*)b;
  #pragma unroll
  for (int i = 0; i < 4; i++) {
    float4 gv = gp[lane+64*i], bv = bp[lane+64*i], o4;
    o4.x = (v[i].x-mu)*inv*gv.x + bv.x;
    o4.y = (v[i].y-mu)*inv*gv.y + bv.y;
    o4.z = (v[i].z-mu)*inv*gv.z + bv.z;
    o4.w = (v[i].w-mu)*inv*gv.w + bv.w;
    p[lane + 64*i] = o4;
  }
}

// ---------------- launch ----------------------------------------------------
extern "C" void kernel_launch(void* const* d_in, const int* in_sizes, int n_in,
                              void* d_out, int out_size, void* d_ws, size_t ws_size,
                              hipStream_t stream) {
  const float* x         = (const float*)d_in[0];
  const float* key_w     = (const float*)d_in[1];
  const float* out_w     = (const float*)d_in[2];
  const float* out_b     = (const float*)d_in[3];
  const float* gate_w    = (const float*)d_in[4];
  const float* gate_b    = (const float*)d_in[5];
  const float* ln_g      = (const float*)d_in[6];
  const float* ln_b      = (const float*)d_in[7];
  const float* pos_table = (const float*)d_in[8];
  const float* mem_keys  = (const float*)d_in[9];
  const float* mem_vals  = (const float*)d_in[10];
  const float* mem_age   = (const float*)d_in[11];
  const float* mem_conf  = (const float*)d_in[12];
  const int*   slot_order= (const int*)d_in[13];

  char* ws = (char*)d_ws;
  u16*   A    = (u16*)(ws + 0);            // combined bf16 [16384][2048]  64 MB
  u16*   Wcat = (u16*)(ws + 67108864);     // interleaved weights [2048][2048] 8 MB
  u16*   Wk   = (u16*)(ws + 75497472);     // key_w  bf16 [32][1024]       64 KB
  u16*   Vals = (u16*)(ws + 75563008);     // mem_vals bf16 [64][1024]    128 KB
  float* kwp  = (float*)(ws + 75694080);   // keys_with_pos [64][33]     8448 B
  float* biasv= (float*)(ws + 75702528);   // salience bias [64]
  float* qk   = (float*)(ws + 75702784);   // qk [16384][32] f32            2 MB
  float* y    = (float*)d_out;

  hipLaunchKernelGGL(k_prep,    dim3(1),    dim3(64),  0, stream,
                     mem_keys, pos_table, slot_order, mem_age, mem_conf, kwp, biasv);
  hipLaunchKernelGGL(k_convert, dim3(8192), dim3(256), 0, stream,
                     x, gate_w, out_w, key_w, mem_vals, A, Wcat, Wk, Vals);
  hipLaunchKernelGGL(k_qk,      dim3(256),  dim3(256), 0, stream, A, Wk, qk);
  hipLaunchKernelGGL(k_retr,    dim3(1024), dim3(256), 0, stream, qk, kwp, biasv, Vals, A);
  hipLaunchKernelGGL(k_gemm,    dim3(512),  dim3(512), 0, stream,
                     A, Wcat, out_b, gate_b, y);
  hipLaunchKernelGGL(k_ln,      dim3(4096), dim3(256), 0, stream, y, ln_g, ln_b);
}